// Round 3
// baseline (1730.800 us; speedup 1.0000x reference)
//
#include <hip/hip_runtime.h>
#include <hip/hip_bf16.h>

#define NB 8
#define NC 16
#define NT 1024
#define DM 128
#define DI 256
#define DS 16
#define DR 8
#define DC 4
#define NL 4
#define NCHUNK 8
#define CL (NT / NCHUNK)      // 128
#define NCHAN 65536           // 2*8*256*16 (r,b,d,s)
#define PT (NB * NT)          // 8192
#define CHW (PT * DI)         // 2,097,152

typedef __attribute__((ext_vector_type(8))) short short8;
typedef __attribute__((ext_vector_type(4))) float floatx4;

#define FLIP(m) (((m) & ~(NT - 1)) | ((NT - 1) - ((m) & (NT - 1))))

// ---------------- weight prep: convert + transpose to bf16 [N][K] ----------------
// region0: in_w  8x[128][512] -> [512][128]   (524288)
// region1: xp_w  8x[256][40]  -> [40][256]    (81920)
// region2: out_w 8x[256][128] -> [128][256]   (262144)
__global__ void wprep_k(const float* __restrict__ in_w, const float* __restrict__ xp_w,
                        const float* __restrict__ out_w, __hip_bfloat16* __restrict__ wT) {
    int i = blockIdx.x * 256 + threadIdx.x;
    if (i < 524288) {
        int g = i >> 16, rem = i & 65535, n = rem >> 7, k = rem & 127;
        wT[i] = __float2bfloat16(in_w[(size_t)g * 65536 + k * 512 + n]);
        return;
    }
    i -= 524288;
    if (i < 81920) {
        int g = i / 10240, rem = i % 10240, n = rem >> 8, k = rem & 255;
        wT[524288 + g * 10240 + n * 256 + k] = __float2bfloat16(xp_w[(size_t)g * 10240 + k * 40 + n]);
        return;
    }
    i -= 81920;
    if (i < 262144) {
        int g = i >> 15, rem = i & 32767, n = rem >> 8, k = rem & 255;
        wT[606208 + g * 32768 + n * 256 + k] = __float2bfloat16(out_w[(size_t)g * 32768 + k * 128 + n]);
    }
}

// ---------------- embed ----------------
__global__ void embed_k(const float* __restrict__ eeg, const float* __restrict__ Win,
                        const float* __restrict__ b_in, float* __restrict__ h) {
    int g = blockIdx.x * 256 + threadIdx.x;
    int m = g & 127;
    int t = (g >> 7) & 1023;
    int b = g >> 17;
    float acc = b_in[m];
#pragma unroll
    for (int c = 0; c < NC; c++)
        acc += eeg[(b * NC + c) * NT + t] * Win[c * DM + m];
    h[g] = acc;
}

// ---------------- layernorm -> bf16 ----------------
__global__ void ln_k(const float* __restrict__ hbuf, const float* __restrict__ w,
                     const float* __restrict__ b, __hip_bfloat16* __restrict__ xn) {
    int lane = threadIdx.x & 63;
    int row = (blockIdx.x * 256 + threadIdx.x) >> 6;
    const float* hr = hbuf + row * DM;
    float v0 = hr[lane], v1 = hr[lane + 64];
    float s = v0 + v1, s2 = v0 * v0 + v1 * v1;
#pragma unroll
    for (int o = 1; o < 64; o <<= 1) {
        s += __shfl_xor(s, o);
        s2 += __shfl_xor(s2, o);
    }
    float mean = s * (1.f / 128.f);
    float var = s2 * (1.f / 128.f) - mean * mean;
    float rs = rsqrtf(var + 1e-5f);
    xn[row * DM + lane]      = __float2bfloat16((v0 - mean) * rs * w[lane] + b[lane]);
    xn[row * DM + lane + 64] = __float2bfloat16((v1 - mean) * rs * w[lane + 64] + b[lane + 64]);
}

// ---------------- bf16 MFMA GEMM: 64x64 tile, 4 waves (2x2), 16x16x32 ----------------
// mode 0: split f32 store cols<split -> O0, else O1 (row stride split each)
// mode 2: O0[cm*N+n] += acc + bias[n], cm row-reversed if revC
__global__ __launch_bounds__(256) void mgemm_k(
    const __hip_bfloat16* __restrict__ A, size_t aStr,
    const __hip_bfloat16* __restrict__ Wt, size_t wStr,
    const float* __restrict__ bias,
    float* __restrict__ O0, size_t oStr0,
    float* __restrict__ O1, size_t oStr1,
    int M, int N, int K, int mode, int revA1, int revC, int split) {
    __shared__ __align__(16) __hip_bfloat16 As[64][40];
    __shared__ __align__(16) __hip_bfloat16 Bs[64][40];
    int z = blockIdx.z;
    A += (size_t)z * aStr;
    Wt += (size_t)z * wStr;
    O0 += (size_t)z * oStr0;
    if (O1) O1 += (size_t)z * oStr1;
    int m0 = blockIdx.x * 64, n0 = blockIdx.y * 64;
    int tid = threadIdx.x;
    int lane = tid & 63, w = tid >> 6;
    int wm = w >> 1, wn = w & 1;
    int lr = lane & 15, lh = lane >> 4;
    int rowL = tid >> 2, cc = tid & 3;
    bool doRev = revA1 && (z == 1);
    floatx4 acc[2][2] = {};
    for (int k0 = 0; k0 < K; k0 += 32) {
        int am = m0 + rowL;
        if (doRev) am = FLIP(am);
        *(float4*)&As[rowL][cc * 8] = *(const float4*)&A[(size_t)am * K + k0 + cc * 8];
        int nn = n0 + rowL;
        float4 bv = {0.f, 0.f, 0.f, 0.f};
        if (nn < N) bv = *(const float4*)&Wt[(size_t)nn * K + k0 + cc * 8];
        *(float4*)&Bs[rowL][cc * 8] = bv;
        __syncthreads();
        short8 a0 = *(const short8*)&As[wm * 32 + lr][lh * 8];
        short8 a1 = *(const short8*)&As[wm * 32 + 16 + lr][lh * 8];
        short8 b0 = *(const short8*)&Bs[wn * 32 + lr][lh * 8];
        short8 b1 = *(const short8*)&Bs[wn * 32 + 16 + lr][lh * 8];
        acc[0][0] = __builtin_amdgcn_mfma_f32_16x16x32_bf16(a0, b0, acc[0][0], 0, 0, 0);
        acc[1][0] = __builtin_amdgcn_mfma_f32_16x16x32_bf16(a1, b0, acc[1][0], 0, 0, 0);
        acc[0][1] = __builtin_amdgcn_mfma_f32_16x16x32_bf16(a0, b1, acc[0][1], 0, 0, 0);
        acc[1][1] = __builtin_amdgcn_mfma_f32_16x16x32_bf16(a1, b1, acc[1][1], 0, 0, 0);
        __syncthreads();
    }
#pragma unroll
    for (int mf = 0; mf < 2; mf++)
#pragma unroll
        for (int nf = 0; nf < 2; nf++)
#pragma unroll
            for (int r = 0; r < 4; r++) {
                int row = m0 + wm * 32 + mf * 16 + lh * 4 + r;
                int col = n0 + wn * 32 + nf * 16 + lr;
                float v = acc[mf][nf][r];
                if (mode == 0) {
                    if (col < split) O0[(size_t)row * split + col] = v;
                    else O1[(size_t)row * split + col - split] = v;
                } else {
                    if (col < N) {
                        int cm = row;
                        if (revC) cm = FLIP(cm);
                        O0[(size_t)cm * N + col] += v + bias[col];
                    }
                }
            }
}

// ---------------- xp GEMM with fused conv+silu A-load; writes xsil bf16 byproduct ----
__global__ __launch_bounds__(256) void xpgemm_k(
    const float* __restrict__ xpre,            // [2][PT][DI] f32
    const __hip_bfloat16* __restrict__ Wt, size_t wStr,  // [2][40][256] bf16
    const float* __restrict__ cw,              // [2][DI][4]
    const float* __restrict__ cb,              // [2][DI]
    float* __restrict__ xdbl,                  // [2][PT][40] f32
    __hip_bfloat16* __restrict__ xsil) {       // [2][PT][DI] bf16
    __shared__ __align__(16) __hip_bfloat16 As[64][40];
    __shared__ __align__(16) __hip_bfloat16 Bs[64][40];
    int z = blockIdx.z;
    const float* xp = xpre + (size_t)z * CHW;
    const __hip_bfloat16* wt = Wt + (size_t)z * wStr;
    const float* cwz = cw + z * DI * DC;
    const float* cbz = cb + z * DI;
    float* xd = xdbl + (size_t)z * PT * 40;
    __hip_bfloat16* xsz = xsil + (size_t)z * CHW;
    int m0 = blockIdx.x * 64;
    int tid = threadIdx.x;
    int lane = tid & 63, w = tid >> 6;
    int wm = w >> 1, wn = w & 1;
    int lr = lane & 15, lh = lane >> 4;
    int rowL = tid >> 2, cc = tid & 3;
    int m = m0 + rowL;
    int tloc = m & (NT - 1);
    floatx4 acc[2][2] = {};
    for (int k0 = 0; k0 < DI; k0 += 32) {
        int d0 = k0 + cc * 8;
        float a8[8];
#pragma unroll
        for (int jj = 0; jj < 8; jj++) a8[jj] = cbz[d0 + jj];
#pragma unroll
        for (int j = 0; j < DC; j++) {
            if (tloc - 3 + j >= 0) {
                const float* src = &xp[(size_t)(m - 3 + j) * DI + d0];
#pragma unroll
                for (int jj = 0; jj < 8; jj++) a8[jj] += src[jj] * cwz[(d0 + jj) * DC + j];
            }
        }
        __align__(16) __hip_bfloat16 h8[8];
#pragma unroll
        for (int jj = 0; jj < 8; jj++) {
            float v = a8[jj];
            v = v / (1.f + __expf(-v));
            h8[jj] = __float2bfloat16(v);
        }
        *(float4*)&As[rowL][cc * 8] = *(const float4*)h8;
        *(float4*)&xsz[(size_t)m * DI + d0] = *(const float4*)h8;
        float4 bv = {0.f, 0.f, 0.f, 0.f};
        if (rowL < 40) bv = *(const float4*)&wt[(size_t)rowL * DI + k0 + cc * 8];
        *(float4*)&Bs[rowL][cc * 8] = bv;
        __syncthreads();
        short8 a0 = *(const short8*)&As[wm * 32 + lr][lh * 8];
        short8 a1 = *(const short8*)&As[wm * 32 + 16 + lr][lh * 8];
        short8 b0 = *(const short8*)&Bs[wn * 32 + lr][lh * 8];
        short8 b1 = *(const short8*)&Bs[wn * 32 + 16 + lr][lh * 8];
        acc[0][0] = __builtin_amdgcn_mfma_f32_16x16x32_bf16(a0, b0, acc[0][0], 0, 0, 0);
        acc[1][0] = __builtin_amdgcn_mfma_f32_16x16x32_bf16(a1, b0, acc[1][0], 0, 0, 0);
        acc[0][1] = __builtin_amdgcn_mfma_f32_16x16x32_bf16(a0, b1, acc[0][1], 0, 0, 0);
        acc[1][1] = __builtin_amdgcn_mfma_f32_16x16x32_bf16(a1, b1, acc[1][1], 0, 0, 0);
        __syncthreads();
    }
#pragma unroll
    for (int mf = 0; mf < 2; mf++)
#pragma unroll
        for (int nf = 0; nf < 2; nf++)
#pragma unroll
            for (int r = 0; r < 4; r++) {
                int row = m0 + wm * 32 + mf * 16 + lh * 4 + r;
                int col = wn * 32 + nf * 16 + lr;
                if (col < 40) xd[(size_t)row * 40 + col] = acc[mf][nf][r];
            }
}

// ---------------- scan pass 1: fused dt (softplus) + chunk summaries + delta store ----
__global__ __launch_bounds__(256) void scan1_k(
    const float* __restrict__ xdbl, const __hip_bfloat16* __restrict__ xsil,
    const float* __restrict__ A_log, const float* __restrict__ dt_w,
    const float* __restrict__ dt_b, float* __restrict__ smry,
    __hip_bfloat16* __restrict__ deltab) {
    int g = blockIdx.x * 256 + threadIdx.x;   // 524288
    int s = g & 15;
    int d = (g >> 4) & 255;
    int b = (g >> 12) & 7;
    int r = (g >> 15) & 1;
    int c = g >> 16;
    int chan = g & (NCHAN - 1);
    size_t cbase = (size_t)r * CHW + (size_t)b * NT * DI + d;
    const __hip_bfloat16* xr = xsil + cbase;
    const float* xd = xdbl + (size_t)r * (PT * 40) + (size_t)b * NT * 40;
    __hip_bfloat16* dlo = deltab + cbase;
    const float* dwr = dt_w + r * DR * DI;
    float dwv[8];
#pragma unroll
    for (int j = 0; j < 8; j++) dwv[j] = dwr[j * DI + d];
    float dtb = dt_b[r * DI + d];
    float Av = -__expf(A_log[(r * DI + d) * DS + s]);
    float ap = 1.f, hh = 0.f;
    int t0 = c * CL;
    for (int t = t0; t < t0 + CL; t++) {
        float4 q0 = *(const float4*)&xd[t * 40];
        float4 q1 = *(const float4*)&xd[t * 40 + 4];
        float dl = dtb + q0.x * dwv[0] + q0.y * dwv[1] + q0.z * dwv[2] + q0.w * dwv[3]
                       + q1.x * dwv[4] + q1.y * dwv[5] + q1.z * dwv[6] + q1.w * dwv[7];
        dl = fmaxf(dl, 0.f) + log1pf(__expf(-fabsf(dl)));
        float xv = __bfloat162float(xr[t * DI]);
        float Bv = xd[t * 40 + DR + s];
        float dA = __expf(dl * Av);
        hh = dA * hh + dl * Bv * xv;
        ap *= dA;
        if (s == 0) dlo[t * DI] = __float2bfloat16(dl);
    }
    smry[c * NCHAN + chan] = ap;
    smry[NCHUNK * NCHAN + c * NCHAN + chan] = hh;
}

// ---------------- scan pass 2: prefix fold + local scan + gated y (bf16) ----------------
__global__ __launch_bounds__(256) void scan2_k(
    const __hip_bfloat16* __restrict__ deltab, const __hip_bfloat16* __restrict__ xsil,
    const float* __restrict__ zb, const float* __restrict__ xdbl,
    const float* __restrict__ A_log, const float* __restrict__ Dp,
    const float* __restrict__ smry, __hip_bfloat16* __restrict__ y) {
    int g = blockIdx.x * 256 + threadIdx.x;   // 524288
    int s = g & 15;
    int d = (g >> 4) & 255;
    int b = (g >> 12) & 7;
    int r = (g >> 15) & 1;
    int c = g >> 16;
    int chan = g & (NCHAN - 1);
    size_t cbase = (size_t)r * CHW + (size_t)b * NT * DI + d;
    const __hip_bfloat16* del = deltab + cbase;
    const __hip_bfloat16* xr = xsil + cbase;
    const float* zr = zb + cbase;
    const float* xd = xdbl + (size_t)r * (PT * 40) + (size_t)b * NT * 40;
    __hip_bfloat16* yr = y + cbase;
    float Av = -__expf(A_log[(r * DI + d) * DS + s]);
    float Dv = Dp[r * DI + d];
    float hh = 0.f;
    for (int j = 0; j < c; j++)
        hh = smry[j * NCHAN + chan] * hh + smry[NCHUNK * NCHAN + j * NCHAN + chan];
    int t0 = c * CL;
    for (int t = t0; t < t0 + CL; t++) {
        float dl = __bfloat162float(del[t * DI]);
        float xv = __bfloat162float(xr[t * DI]);
        float Bv = xd[t * 40 + DR + s];
        float Cv = xd[t * 40 + DR + DS + s];
        float dA = __expf(dl * Av);
        hh = dA * hh + dl * Bv * xv;
        float py = hh * Cv;
        py += __shfl_xor(py, 1);
        py += __shfl_xor(py, 2);
        py += __shfl_xor(py, 4);
        py += __shfl_xor(py, 8);
        if (s == 0) {
            float zv = zr[t * DI];
            float sig = 1.f / (1.f + __expf(-zv));
            yr[t * DI] = __float2bfloat16((py + Dv * xv) * (zv * sig));
        }
    }
}

// ---------------- mean pool ----------------
__global__ void pool_k(const float* __restrict__ h, float* __restrict__ pooled) {
    int b = blockIdx.x, m = threadIdx.x;
    float acc = 0.f;
    for (int t = 0; t < NT; t++) acc += h[(b * NT + t) * DM + m];
    pooled[b * DM + m] = acc * (1.f / NT);
}

// ---------------- classifier ----------------
__global__ __launch_bounds__(128) void cls_k(
    const float* __restrict__ pooled, const float* __restrict__ lw,
    const float* __restrict__ lb, const float* __restrict__ W1,
    const float* __restrict__ b1, const float* __restrict__ W2,
    const float* __restrict__ b2, float* __restrict__ out) {
    __shared__ float red[128], pbuf[128], qbuf[64];
    int b = blockIdx.x, i = threadIdx.x;
    float v = pooled[b * DM + i];
    red[i] = v;
    __syncthreads();
    for (int o = 64; o > 0; o >>= 1) { if (i < o) red[i] += red[i + o]; __syncthreads(); }
    float mean = red[0] * (1.f / 128.f);
    __syncthreads();
    red[i] = (v - mean) * (v - mean);
    __syncthreads();
    for (int o = 64; o > 0; o >>= 1) { if (i < o) red[i] += red[i + o]; __syncthreads(); }
    float var = red[0] * (1.f / 128.f);
    float p = (v - mean) * rsqrtf(var + 1e-5f) * lw[i] + lb[i];
    pbuf[i] = p;
    __syncthreads();
    if (i < 64) {
        float acc = b1[i];
        for (int k = 0; k < 128; k++) acc += pbuf[k] * W1[k * 64 + i];
        float x = acc;
        float tt = tanhf(0.7978845608028654f * (x + 0.044715f * x * x * x));
        qbuf[i] = 0.5f * x * (1.f + tt);
    }
    __syncthreads();
    if (i == 0) {
        float acc = b2[0];
        for (int k = 0; k < 64; k++) acc += qbuf[k] * W2[k];
        out[b] = acc;
    }
}

extern "C" void kernel_launch(void* const* d_in, const int* in_sizes, int n_in,
                              void* d_out, int out_size, void* d_ws, size_t ws_size,
                              hipStream_t stream) {
    const float* eeg    = (const float*)d_in[0];
    const float* Win    = (const float*)d_in[1];
    const float* b_in   = (const float*)d_in[2];
    const float* ln_w   = (const float*)d_in[3];
    const float* ln_b   = (const float*)d_in[4];
    const float* in_w   = (const float*)d_in[5];
    const float* conv_w = (const float*)d_in[6];
    const float* conv_b = (const float*)d_in[7];
    const float* xp_w   = (const float*)d_in[8];
    const float* dt_w   = (const float*)d_in[9];
    const float* dt_b   = (const float*)d_in[10];
    const float* A_log  = (const float*)d_in[11];
    const float* Dp     = (const float*)d_in[12];
    const float* out_w  = (const float*)d_in[13];
    const float* out_b  = (const float*)d_in[14];
    const float* clw    = (const float*)d_in[15];
    const float* clb    = (const float*)d_in[16];
    const float* W1     = (const float*)d_in[17];
    const float* b1     = (const float*)d_in[18];
    const float* W2     = (const float*)d_in[19];
    const float* b2     = (const float*)d_in[20];
    float* out = (float*)d_out;

    float* ws = (float*)d_ws;
    float* h      = ws;                          // 1,048,576
    float* xpre   = h + PT * DM;                 // 4,194,304  [2][PT][DI]
    float* zbuf   = xpre + 2 * CHW;              // 4,194,304
    float* xdbl   = zbuf + 2 * CHW;              // 655,360   [2][PT][40]
    float* smry   = xdbl + 2 * PT * 40;          // 1,048,576
    float* pooled = smry + 2 * NCHUNK * NCHAN;   // 1,024
    __hip_bfloat16* xnb    = (__hip_bfloat16*)(pooled + 1024);  // 1,048,576
    __hip_bfloat16* xsilb  = xnb + PT * DM;                     // 4,194,304
    __hip_bfloat16* deltab = xsilb + 2 * CHW;                   // 4,194,304
    __hip_bfloat16* yb     = deltab + 2 * CHW;                  // 4,194,304
    __hip_bfloat16* wT     = yb + 2 * CHW;                      // 868,352
    __hip_bfloat16* wTin   = wT;                 // 8 x [512][128]
    __hip_bfloat16* wTxp   = wT + 524288;        // 8 x [40][256]
    __hip_bfloat16* wTout  = wT + 606208;        // 8 x [128][256]

    wprep_k<<<3392, 256, 0, stream>>>(in_w, xp_w, out_w, wT);
    embed_k<<<PT * DM / 256, 256, 0, stream>>>(eeg, Win, b_in, h);

    for (int l = 0; l < NL; l++) {
        ln_k<<<PT / 4, 256, 0, stream>>>(h, ln_w + l * DM, ln_b + l * DM, xnb);
        // xz = xn(rev for z=1) @ in_w -> xpre | zbuf   (M=8192, N=512, K=128)
        mgemm_k<<<dim3(PT / 64, 8, 2), 256, 0, stream>>>(
            xnb, 0, wTin + (size_t)l * 2 * 65536, 65536, nullptr,
            xpre, CHW, zbuf, CHW, PT, 2 * DI, DM, 0, 1, 0, DI);
        // xdbl = silu(conv(xpre)) @ xp_w; byproduct xsil bf16  (M=8192, N=40, K=256)
        xpgemm_k<<<dim3(PT / 64, 1, 2), 256, 0, stream>>>(
            xpre, wTxp + (size_t)l * 2 * 10240, 10240,
            conv_w + (size_t)l * 2 * DI * DC, conv_b + (size_t)l * 2 * DI,
            xdbl, xsilb);
        // chunked scan with fused dt
        scan1_k<<<NCHUNK * NCHAN / 256, 256, 0, stream>>>(
            xdbl, xsilb, A_log + (size_t)l * 2 * DI * DS,
            dt_w + (size_t)l * 2 * DR * DI, dt_b + (size_t)l * 2 * DI, smry, deltab);
        scan2_k<<<NCHUNK * NCHAN / 256, 256, 0, stream>>>(
            deltab, xsilb, zbuf, xdbl, A_log + (size_t)l * 2 * DI * DS,
            Dp + (size_t)l * 2 * DI, smry, yb);
        // h[rev?] += y @ out_w + out_b  (M=8192, N=128, K=256); separate launches avoid RMW race
        for (int r = 0; r < 2; r++) {
            mgemm_k<<<dim3(PT / 64, 2, 1), 256, 0, stream>>>(
                yb + (size_t)r * CHW, 0, wTout + (size_t)(l * 2 + r) * 32768, 0,
                out_b + (size_t)(l * 2 + r) * DM, h, 0, nullptr, 0,
                PT, DM, DI, 2, 0, r, 0);
        }
    }

    pool_k<<<NB, DM, 0, stream>>>(h, pooled);
    cls_k<<<NB, DM, 0, stream>>>(pooled, clw, clb, W1, b1, W2, b2, out);
}

// Round 4
// 754.796 us; speedup vs baseline: 2.2931x; 2.2931x over previous
//
#include <hip/hip_runtime.h>
#include <hip/hip_bf16.h>

#define NB 8
#define NC 16
#define NT 1024
#define DM 128
#define DI 256
#define DS 16
#define DR 8
#define DC 4
#define NL 4
#define NCHUNK 32
#define CL (NT / NCHUNK)      // 32
#define NCH 4096              // 2*8*256 channels (r,b,d)
#define PT (NB * NT)          // 8192
#define CHW (PT * DI)         // 2,097,152

typedef __attribute__((ext_vector_type(8))) short short8;
typedef __attribute__((ext_vector_type(4))) float floatx4;

#define FLIP(m) (((m) & ~(NT - 1)) | ((NT - 1) - ((m) & (NT - 1))))

// ---------------- weight prep: convert + transpose to bf16 [N][K] ----------------
__global__ void wprep_k(const float* __restrict__ in_w, const float* __restrict__ xp_w,
                        const float* __restrict__ out_w, __hip_bfloat16* __restrict__ wT) {
    int i = blockIdx.x * 256 + threadIdx.x;
    if (i < 524288) {
        int g = i >> 16, rem = i & 65535, n = rem >> 7, k = rem & 127;
        wT[i] = __float2bfloat16(in_w[(size_t)g * 65536 + k * 512 + n]);
        return;
    }
    i -= 524288;
    if (i < 81920) {
        int g = i / 10240, rem = i % 10240, n = rem >> 8, k = rem & 255;
        wT[524288 + g * 10240 + n * 256 + k] = __float2bfloat16(xp_w[(size_t)g * 10240 + k * 40 + n]);
        return;
    }
    i -= 81920;
    if (i < 262144) {
        int g = i >> 15, rem = i & 32767, n = rem >> 8, k = rem & 255;
        wT[606208 + g * 32768 + n * 256 + k] = __float2bfloat16(out_w[(size_t)g * 32768 + k * 128 + n]);
    }
}

// ---------------- embed ----------------
__global__ void embed_k(const float* __restrict__ eeg, const float* __restrict__ Win,
                        const float* __restrict__ b_in, float* __restrict__ h) {
    int g = blockIdx.x * 256 + threadIdx.x;
    int m = g & 127;
    int t = (g >> 7) & 1023;
    int b = g >> 17;
    float acc = b_in[m];
#pragma unroll
    for (int c = 0; c < NC; c++)
        acc += eeg[(b * NC + c) * NT + t] * Win[c * DM + m];
    h[g] = acc;
}

// ---------------- layernorm -> bf16 ----------------
__global__ void ln_k(const float* __restrict__ hbuf, const float* __restrict__ w,
                     const float* __restrict__ b, __hip_bfloat16* __restrict__ xn) {
    int lane = threadIdx.x & 63;
    int row = (blockIdx.x * 256 + threadIdx.x) >> 6;
    const float* hr = hbuf + row * DM;
    float v0 = hr[lane], v1 = hr[lane + 64];
    float s = v0 + v1, s2 = v0 * v0 + v1 * v1;
#pragma unroll
    for (int o = 1; o < 64; o <<= 1) {
        s += __shfl_xor(s, o);
        s2 += __shfl_xor(s2, o);
    }
    float mean = s * (1.f / 128.f);
    float var = s2 * (1.f / 128.f) - mean * mean;
    float rs = rsqrtf(var + 1e-5f);
    xn[row * DM + lane]      = __float2bfloat16((v0 - mean) * rs * w[lane] + b[lane]);
    xn[row * DM + lane + 64] = __float2bfloat16((v1 - mean) * rs * w[lane + 64] + b[lane + 64]);
}

// ---------------- bf16 MFMA GEMM: 64x64 tile, 4 waves (2x2), 16x16x32 ----------------
__global__ __launch_bounds__(256) void mgemm_k(
    const __hip_bfloat16* __restrict__ A, size_t aStr,
    const __hip_bfloat16* __restrict__ Wt, size_t wStr,
    const float* __restrict__ bias,
    float* __restrict__ O0, size_t oStr0,
    float* __restrict__ O1, size_t oStr1,
    int M, int N, int K, int mode, int revA1, int revC, int split) {
    __shared__ __align__(16) __hip_bfloat16 As[64][40];
    __shared__ __align__(16) __hip_bfloat16 Bs[64][40];
    int z = blockIdx.z;
    A += (size_t)z * aStr;
    Wt += (size_t)z * wStr;
    O0 += (size_t)z * oStr0;
    if (O1) O1 += (size_t)z * oStr1;
    int m0 = blockIdx.x * 64, n0 = blockIdx.y * 64;
    int tid = threadIdx.x;
    int lane = tid & 63, w = tid >> 6;
    int wm = w >> 1, wn = w & 1;
    int lr = lane & 15, lh = lane >> 4;
    int rowL = tid >> 2, cc = tid & 3;
    bool doRev = revA1 && (z == 1);
    floatx4 acc[2][2] = {};
    for (int k0 = 0; k0 < K; k0 += 32) {
        int am = m0 + rowL;
        if (doRev) am = FLIP(am);
        *(float4*)&As[rowL][cc * 8] = *(const float4*)&A[(size_t)am * K + k0 + cc * 8];
        int nn = n0 + rowL;
        float4 bv = {0.f, 0.f, 0.f, 0.f};
        if (nn < N) bv = *(const float4*)&Wt[(size_t)nn * K + k0 + cc * 8];
        *(float4*)&Bs[rowL][cc * 8] = bv;
        __syncthreads();
        short8 a0 = *(const short8*)&As[wm * 32 + lr][lh * 8];
        short8 a1 = *(const short8*)&As[wm * 32 + 16 + lr][lh * 8];
        short8 b0 = *(const short8*)&Bs[wn * 32 + lr][lh * 8];
        short8 b1 = *(const short8*)&Bs[wn * 32 + 16 + lr][lh * 8];
        acc[0][0] = __builtin_amdgcn_mfma_f32_16x16x32_bf16(a0, b0, acc[0][0], 0, 0, 0);
        acc[1][0] = __builtin_amdgcn_mfma_f32_16x16x32_bf16(a1, b0, acc[1][0], 0, 0, 0);
        acc[0][1] = __builtin_amdgcn_mfma_f32_16x16x32_bf16(a0, b1, acc[0][1], 0, 0, 0);
        acc[1][1] = __builtin_amdgcn_mfma_f32_16x16x32_bf16(a1, b1, acc[1][1], 0, 0, 0);
        __syncthreads();
    }
#pragma unroll
    for (int mf = 0; mf < 2; mf++)
#pragma unroll
        for (int nf = 0; nf < 2; nf++)
#pragma unroll
            for (int r = 0; r < 4; r++) {
                int row = m0 + wm * 32 + mf * 16 + lh * 4 + r;
                int col = n0 + wn * 32 + nf * 16 + lr;
                float v = acc[mf][nf][r];
                if (mode == 0) {
                    if (col < split) O0[(size_t)row * split + col] = v;
                    else O1[(size_t)row * split + col - split] = v;
                } else {
                    if (col < N) {
                        int cm = row;
                        if (revC) cm = FLIP(cm);
                        O0[(size_t)cm * N + col] += v + bias[col];
                    }
                }
            }
}

// ---------------- xp GEMM with fused conv+silu A-load; writes xsil bf16 byproduct ----
__global__ __launch_bounds__(256) void xpgemm_k(
    const float* __restrict__ xpre,
    const __hip_bfloat16* __restrict__ Wt, size_t wStr,
    const float* __restrict__ cw, const float* __restrict__ cb,
    float* __restrict__ xdbl, __hip_bfloat16* __restrict__ xsil) {
    __shared__ __align__(16) __hip_bfloat16 As[64][40];
    __shared__ __align__(16) __hip_bfloat16 Bs[64][40];
    int z = blockIdx.z;
    const float* xp = xpre + (size_t)z * CHW;
    const __hip_bfloat16* wt = Wt + (size_t)z * wStr;
    const float* cwz = cw + z * DI * DC;
    const float* cbz = cb + z * DI;
    float* xd = xdbl + (size_t)z * PT * 40;
    __hip_bfloat16* xsz = xsil + (size_t)z * CHW;
    int m0 = blockIdx.x * 64;
    int tid = threadIdx.x;
    int lane = tid & 63, w = tid >> 6;
    int wm = w >> 1, wn = w & 1;
    int lr = lane & 15, lh = lane >> 4;
    int rowL = tid >> 2, cc = tid & 3;
    int m = m0 + rowL;
    int tloc = m & (NT - 1);
    floatx4 acc[2][2] = {};
    for (int k0 = 0; k0 < DI; k0 += 32) {
        int d0 = k0 + cc * 8;
        float a8[8];
#pragma unroll
        for (int jj = 0; jj < 8; jj++) a8[jj] = cbz[d0 + jj];
#pragma unroll
        for (int j = 0; j < DC; j++) {
            if (tloc - 3 + j >= 0) {
                const float* src = &xp[(size_t)(m - 3 + j) * DI + d0];
#pragma unroll
                for (int jj = 0; jj < 8; jj++) a8[jj] += src[jj] * cwz[(d0 + jj) * DC + j];
            }
        }
        __align__(16) __hip_bfloat16 h8[8];
#pragma unroll
        for (int jj = 0; jj < 8; jj++) {
            float v = a8[jj];
            v = v / (1.f + __expf(-v));
            h8[jj] = __float2bfloat16(v);
        }
        *(float4*)&As[rowL][cc * 8] = *(const float4*)h8;
        *(float4*)&xsz[(size_t)m * DI + d0] = *(const float4*)h8;
        float4 bv = {0.f, 0.f, 0.f, 0.f};
        if (rowL < 40) bv = *(const float4*)&wt[(size_t)rowL * DI + k0 + cc * 8];
        *(float4*)&Bs[rowL][cc * 8] = bv;
        __syncthreads();
        short8 a0 = *(const short8*)&As[wm * 32 + lr][lh * 8];
        short8 a1 = *(const short8*)&As[wm * 32 + 16 + lr][lh * 8];
        short8 b0 = *(const short8*)&Bs[wn * 32 + lr][lh * 8];
        short8 b1 = *(const short8*)&Bs[wn * 32 + 16 + lr][lh * 8];
        acc[0][0] = __builtin_amdgcn_mfma_f32_16x16x32_bf16(a0, b0, acc[0][0], 0, 0, 0);
        acc[1][0] = __builtin_amdgcn_mfma_f32_16x16x32_bf16(a1, b0, acc[1][0], 0, 0, 0);
        acc[0][1] = __builtin_amdgcn_mfma_f32_16x16x32_bf16(a0, b1, acc[0][1], 0, 0, 0);
        acc[1][1] = __builtin_amdgcn_mfma_f32_16x16x32_bf16(a1, b1, acc[1][1], 0, 0, 0);
        __syncthreads();
    }
#pragma unroll
    for (int mf = 0; mf < 2; mf++)
#pragma unroll
        for (int nf = 0; nf < 2; nf++)
#pragma unroll
            for (int r = 0; r < 4; r++) {
                int row = m0 + wm * 32 + mf * 16 + lh * 4 + r;
                int col = wn * 32 + nf * 16 + lr;
                if (col < 40) xd[(size_t)row * 40 + col] = acc[mf][nf][r];
            }
}

// ---------------- dt: delta = softplus(dt @ dt_w + dt_b) -> bf16, once per (t,d) ----
__global__ void dt_k(const float* __restrict__ xdbl, const float* __restrict__ dt_w,
                     const float* __restrict__ dt_b, __hip_bfloat16* __restrict__ deltab) {
    int g = blockIdx.x * 256 + threadIdx.x;   // 2*PT*DI = 4,194,304
    int d = g & 255;
    int row = g >> 8;                          // [0, 16384)
    int r = row >> 13;
    const float* xr = xdbl + (size_t)row * 40;
    float acc = dt_b[r * DI + d];
#pragma unroll
    for (int j = 0; j < DR; j++)
        acc += xr[j] * dt_w[(r * DR + j) * DI + d];
    float sp = fmaxf(acc, 0.f) + log1pf(__expf(-fabsf(acc)));
    deltab[g] = __float2bfloat16(sp);
}

// ---------------- scan pass 1: one lane per channel, 16 states in registers ----------
// g: chan = g & 4095 (d=chan&255, b=(chan>>8)&7, r=chan>>11), c = g>>12
__global__ __launch_bounds__(256) void scan1_k(
    const __hip_bfloat16* __restrict__ deltab, const __hip_bfloat16* __restrict__ xsil,
    const float* __restrict__ xdbl, const float* __restrict__ A_log,
    float* __restrict__ smryA, float* __restrict__ smryH) {
    int g = blockIdx.x * 256 + threadIdx.x;   // NCHUNK*NCH = 131072
    int chan = g & (NCH - 1), c = g >> 12;
    int d = chan & 255, b = (chan >> 8) & 7, r = chan >> 11;
    size_t cbase = (size_t)(r * 8 + b) * (NT * DI) + d;
    const __hip_bfloat16* del = deltab + cbase;
    const __hip_bfloat16* xr = xsil + cbase;
    const float* xd = xdbl + (size_t)(r * PT + b * NT) * 40;
    float Av[16], hs[16], ap[16];
#pragma unroll
    for (int s = 0; s < 16; s++) {
        Av[s] = -__expf(A_log[(r * DI + d) * DS + s]);
        hs[s] = 0.f;
        ap[s] = 1.f;
    }
    int t0 = c * CL;
    for (int t = t0; t < t0 + CL; t++) {
        float dl = __bfloat162float(del[t * DI]);
        float xv = __bfloat162float(xr[t * DI]);
        float u = dl * xv;
        float Bv[16];
        const float4* bp = (const float4*)(xd + t * 40 + DR);
        *(float4*)&Bv[0] = bp[0]; *(float4*)&Bv[4] = bp[1];
        *(float4*)&Bv[8] = bp[2]; *(float4*)&Bv[12] = bp[3];
#pragma unroll
        for (int s = 0; s < 16; s++) {
            float dA = __expf(dl * Av[s]);
            ap[s] *= dA;
            hs[s] = dA * hs[s] + u * Bv[s];
        }
    }
    float* sa = smryA + (size_t)(c * NCH + chan) * 16;
    float* sh = smryH + (size_t)(c * NCH + chan) * 16;
#pragma unroll
    for (int s = 0; s < 16; s += 4) {
        *(float4*)&sa[s] = *(const float4*)&ap[s];
        *(float4*)&sh[s] = *(const float4*)&hs[s];
    }
}

// ---------------- scan pass 2: inline prefix fold + local scan + gated y (bf16) ------
__global__ __launch_bounds__(256) void scan2_k(
    const __hip_bfloat16* __restrict__ deltab, const __hip_bfloat16* __restrict__ xsil,
    const float* __restrict__ zbuf, const float* __restrict__ xdbl,
    const float* __restrict__ A_log, const float* __restrict__ Dp,
    const float* __restrict__ smryA, const float* __restrict__ smryH,
    __hip_bfloat16* __restrict__ y) {
    int g = blockIdx.x * 256 + threadIdx.x;   // 131072
    int chan = g & (NCH - 1), c = g >> 12;
    int d = chan & 255, b = (chan >> 8) & 7, r = chan >> 11;
    size_t cbase = (size_t)(r * 8 + b) * (NT * DI) + d;
    const __hip_bfloat16* del = deltab + cbase;
    const __hip_bfloat16* xr = xsil + cbase;
    const float* zr = zbuf + cbase;
    const float* xd = xdbl + (size_t)(r * PT + b * NT) * 40;
    __hip_bfloat16* yr = y + cbase;
    float Av[16], hs[16];
#pragma unroll
    for (int s = 0; s < 16; s++) {
        Av[s] = -__expf(A_log[(r * DI + d) * DS + s]);
        hs[s] = 0.f;
    }
    for (int j = 0; j < c; j++) {
        const float4* aj = (const float4*)(smryA + (size_t)(j * NCH + chan) * 16);
        const float4* hj = (const float4*)(smryH + (size_t)(j * NCH + chan) * 16);
        float apj[16], hhj[16];
#pragma unroll
        for (int s = 0; s < 16; s += 4) {
            *(float4*)&apj[s] = aj[s >> 2];
            *(float4*)&hhj[s] = hj[s >> 2];
        }
#pragma unroll
        for (int s = 0; s < 16; s++) hs[s] = apj[s] * hs[s] + hhj[s];
    }
    float Dv = Dp[r * DI + d];
    int t0 = c * CL;
    for (int t = t0; t < t0 + CL; t++) {
        float dl = __bfloat162float(del[t * DI]);
        float xv = __bfloat162float(xr[t * DI]);
        float u = dl * xv;
        float Bv[16], Cv[16];
        const float4* bp = (const float4*)(xd + t * 40 + DR);
        *(float4*)&Bv[0] = bp[0]; *(float4*)&Bv[4] = bp[1];
        *(float4*)&Bv[8] = bp[2]; *(float4*)&Bv[12] = bp[3];
        const float4* cp = (const float4*)(xd + t * 40 + DR + DS);
        *(float4*)&Cv[0] = cp[0]; *(float4*)&Cv[4] = cp[1];
        *(float4*)&Cv[8] = cp[2]; *(float4*)&Cv[12] = cp[3];
        float py = 0.f;
#pragma unroll
        for (int s = 0; s < 16; s++) {
            float dA = __expf(dl * Av[s]);
            hs[s] = dA * hs[s] + u * Bv[s];
            py += hs[s] * Cv[s];
        }
        float zv = zr[t * DI];
        float sig = 1.f / (1.f + __expf(-zv));
        yr[t * DI] = __float2bfloat16((py + Dv * xv) * (zv * sig));
    }
}

// ---------------- mean pool ----------------
__global__ void pool_k(const float* __restrict__ h, float* __restrict__ pooled) {
    int b = blockIdx.x, m = threadIdx.x;
    float acc = 0.f;
    for (int t = 0; t < NT; t++) acc += h[(b * NT + t) * DM + m];
    pooled[b * DM + m] = acc * (1.f / NT);
}

// ---------------- classifier ----------------
__global__ __launch_bounds__(128) void cls_k(
    const float* __restrict__ pooled, const float* __restrict__ lw,
    const float* __restrict__ lb, const float* __restrict__ W1,
    const float* __restrict__ b1, const float* __restrict__ W2,
    const float* __restrict__ b2, float* __restrict__ out) {
    __shared__ float red[128], pbuf[128], qbuf[64];
    int b = blockIdx.x, i = threadIdx.x;
    float v = pooled[b * DM + i];
    red[i] = v;
    __syncthreads();
    for (int o = 64; o > 0; o >>= 1) { if (i < o) red[i] += red[i + o]; __syncthreads(); }
    float mean = red[0] * (1.f / 128.f);
    __syncthreads();
    red[i] = (v - mean) * (v - mean);
    __syncthreads();
    for (int o = 64; o > 0; o >>= 1) { if (i < o) red[i] += red[i + o]; __syncthreads(); }
    float var = red[0] * (1.f / 128.f);
    float p = (v - mean) * rsqrtf(var + 1e-5f) * lw[i] + lb[i];
    pbuf[i] = p;
    __syncthreads();
    if (i < 64) {
        float acc = b1[i];
        for (int k = 0; k < 128; k++) acc += pbuf[k] * W1[k * 64 + i];
        float x = acc;
        float tt = tanhf(0.7978845608028654f * (x + 0.044715f * x * x * x));
        qbuf[i] = 0.5f * x * (1.f + tt);
    }
    __syncthreads();
    if (i == 0) {
        float acc = b2[0];
        for (int k = 0; k < 64; k++) acc += qbuf[k] * W2[k];
        out[b] = acc;
    }
}

extern "C" void kernel_launch(void* const* d_in, const int* in_sizes, int n_in,
                              void* d_out, int out_size, void* d_ws, size_t ws_size,
                              hipStream_t stream) {
    const float* eeg    = (const float*)d_in[0];
    const float* Win    = (const float*)d_in[1];
    const float* b_in   = (const float*)d_in[2];
    const float* ln_w   = (const float*)d_in[3];
    const float* ln_b   = (const float*)d_in[4];
    const float* in_w   = (const float*)d_in[5];
    const float* conv_w = (const float*)d_in[6];
    const float* conv_b = (const float*)d_in[7];
    const float* xp_w   = (const float*)d_in[8];
    const float* dt_w   = (const float*)d_in[9];
    const float* dt_b   = (const float*)d_in[10];
    const float* A_log  = (const float*)d_in[11];
    const float* Dp     = (const float*)d_in[12];
    const float* out_w  = (const float*)d_in[13];
    const float* out_b  = (const float*)d_in[14];
    const float* clw    = (const float*)d_in[15];
    const float* clb    = (const float*)d_in[16];
    const float* W1     = (const float*)d_in[17];
    const float* b1     = (const float*)d_in[18];
    const float* W2     = (const float*)d_in[19];
    const float* b2     = (const float*)d_in[20];
    float* out = (float*)d_out;

    float* ws = (float*)d_ws;
    float* h      = ws;                          // 1,048,576 f32
    float* xpre   = h + PT * DM;                 // 4,194,304 f32 [2][PT][DI]; reused as smryA|smryH
    float* zbuf   = xpre + 2 * CHW;              // 4,194,304 f32
    float* xdbl   = zbuf + 2 * CHW;              // 655,360 f32 [2][PT][40]
    float* pooled = xdbl + 2 * PT * 40;          // 1,024 f32
    __hip_bfloat16* xnb    = (__hip_bfloat16*)(pooled + 1024);  // 1,048,576 bf16
    __hip_bfloat16* xsilb  = xnb + PT * DM;                     // 4,194,304 bf16
    __hip_bfloat16* deltab = xsilb + 2 * CHW;                   // 4,194,304 bf16
    __hip_bfloat16* yb     = deltab + 2 * CHW;                  // 4,194,304 bf16
    __hip_bfloat16* wT     = yb + 2 * CHW;                      // 868,352 bf16
    __hip_bfloat16* wTin   = wT;
    __hip_bfloat16* wTxp   = wT + 524288;
    __hip_bfloat16* wTout  = wT + 606208;
    // scan summaries overlap xpre (dead after xpgemm, rewritten next layer's mgemm_in)
    float* smryA = xpre;                         // NCHUNK*NCH*16 = 2,097,152
    float* smryH = xpre + NCHUNK * NCH * 16;     // 2,097,152

    wprep_k<<<3392, 256, 0, stream>>>(in_w, xp_w, out_w, wT);
    embed_k<<<PT * DM / 256, 256, 0, stream>>>(eeg, Win, b_in, h);

    for (int l = 0; l < NL; l++) {
        ln_k<<<PT / 4, 256, 0, stream>>>(h, ln_w + l * DM, ln_b + l * DM, xnb);
        // xz = xn(rev for z=1) @ in_w -> xpre | zbuf   (M=8192, N=512, K=128)
        mgemm_k<<<dim3(PT / 64, 8, 2), 256, 0, stream>>>(
            xnb, 0, wTin + (size_t)l * 2 * 65536, 65536, nullptr,
            xpre, CHW, zbuf, CHW, PT, 2 * DI, DM, 0, 1, 0, DI);
        // xdbl = silu(conv(xpre)) @ xp_w; byproduct xsil bf16  (M=8192, N=40, K=256)
        xpgemm_k<<<dim3(PT / 64, 1, 2), 256, 0, stream>>>(
            xpre, wTxp + (size_t)l * 2 * 10240, 10240,
            conv_w + (size_t)l * 2 * DI * DC, conv_b + (size_t)l * 2 * DI,
            xdbl, xsilb);
        // delta once per (t,d)
        dt_k<<<2 * CHW / 256, 256, 0, stream>>>(
            xdbl, dt_w + (size_t)l * 2 * DR * DI, dt_b + (size_t)l * 2 * DI, deltab);
        // chunked scan, 1 lane per channel, 16 states in registers
        scan1_k<<<NCHUNK * NCH / 256, 256, 0, stream>>>(
            deltab, xsilb, xdbl, A_log + (size_t)l * 2 * DI * DS, smryA, smryH);
        scan2_k<<<NCHUNK * NCH / 256, 256, 0, stream>>>(
            deltab, xsilb, zbuf, xdbl, A_log + (size_t)l * 2 * DI * DS,
            Dp + (size_t)l * 2 * DI, smryA, smryH, yb);
        // h[rev?] += y @ out_w + out_b  (M=8192, N=128, K=256)
        for (int r = 0; r < 2; r++) {
            mgemm_k<<<dim3(PT / 64, 2, 1), 256, 0, stream>>>(
                yb + (size_t)r * CHW, 0, wTout + (size_t)(l * 2 + r) * 32768, 0,
                out_b + (size_t)(l * 2 + r) * DM, h, 0, nullptr, 0,
                PT, DM, DI, 2, 0, r, 0);
        }
    }

    pool_k<<<NB, DM, 0, stream>>>(h, pooled);
    cls_k<<<NB, DM, 0, stream>>>(pooled, clw, clb, W1, b1, W2, b2, out);
}

// Round 5
// 510.507 us; speedup vs baseline: 3.3904x; 1.4785x over previous
//
#include <hip/hip_runtime.h>
#include <hip/hip_bf16.h>

#define NB 8
#define NC 16
#define NT 1024
#define DM 128
#define DI 256
#define DS 16
#define DR 8
#define DC 4
#define NL 4
#define NCHUNK 32
#define CL (NT / NCHUNK)      // 32
#define NCH 4096              // 2*8*256 channels (r,b,d)
#define PT (NB * NT)          // 8192
#define CHW (PT * DI)         // 2,097,152

typedef __attribute__((ext_vector_type(8))) short short8;
typedef __attribute__((ext_vector_type(4))) float floatx4;

#define FLIP(m) (((m) & ~(NT - 1)) | ((NT - 1) - ((m) & (NT - 1))))

// ---------------- weight prep: convert + transpose to bf16 [N][K] ----------------
__global__ void wprep_k(const float* __restrict__ in_w, const float* __restrict__ xp_w,
                        const float* __restrict__ out_w, __hip_bfloat16* __restrict__ wT) {
    int i = blockIdx.x * 256 + threadIdx.x;
    if (i < 524288) {
        int g = i >> 16, rem = i & 65535, n = rem >> 7, k = rem & 127;
        wT[i] = __float2bfloat16(in_w[(size_t)g * 65536 + k * 512 + n]);
        return;
    }
    i -= 524288;
    if (i < 81920) {
        int g = i / 10240, rem = i % 10240, n = rem >> 8, k = rem & 255;
        wT[524288 + g * 10240 + n * 256 + k] = __float2bfloat16(xp_w[(size_t)g * 10240 + k * 40 + n]);
        return;
    }
    i -= 81920;
    if (i < 262144) {
        int g = i >> 15, rem = i & 32767, n = rem >> 8, k = rem & 255;
        wT[606208 + g * 32768 + n * 256 + k] = __float2bfloat16(out_w[(size_t)g * 32768 + k * 128 + n]);
    }
}

// ---------------- embed ----------------
__global__ void embed_k(const float* __restrict__ eeg, const float* __restrict__ Win,
                        const float* __restrict__ b_in, float* __restrict__ h) {
    int g = blockIdx.x * 256 + threadIdx.x;
    int m = g & 127;
    int t = (g >> 7) & 1023;
    int b = g >> 17;
    float acc = b_in[m];
#pragma unroll
    for (int c = 0; c < NC; c++)
        acc += eeg[(b * NC + c) * NT + t] * Win[c * DM + m];
    h[g] = acc;
}

// ---------------- residual add (fwd + flipped bwd) + layernorm -> bf16 ----------------
__global__ void lnadd_k(float* __restrict__ hbuf, const float* __restrict__ ytmp,
                        const float* __restrict__ w, const float* __restrict__ b,
                        __hip_bfloat16* __restrict__ xn, int doAdd) {
    int lane = threadIdx.x & 63;
    int row = (blockIdx.x * 256 + threadIdx.x) >> 6;
    float* hr = hbuf + (size_t)row * DM;
    float v0 = hr[lane], v1 = hr[lane + 64];
    if (doAdd) {
        const float* y0 = ytmp + (size_t)row * DM;
        const float* y1 = ytmp + (size_t)PT * DM + (size_t)FLIP(row) * DM;
        v0 += y0[lane] + y1[lane];
        v1 += y0[lane + 64] + y1[lane + 64];
        hr[lane] = v0;
        hr[lane + 64] = v1;
    }
    float s = v0 + v1, s2 = v0 * v0 + v1 * v1;
#pragma unroll
    for (int o = 1; o < 64; o <<= 1) {
        s += __shfl_xor(s, o);
        s2 += __shfl_xor(s2, o);
    }
    float mean = s * (1.f / 128.f);
    float var = s2 * (1.f / 128.f) - mean * mean;
    float rs = rsqrtf(var + 1e-5f);
    xn[(size_t)row * DM + lane]      = __float2bfloat16((v0 - mean) * rs * w[lane] + b[lane]);
    xn[(size_t)row * DM + lane + 64] = __float2bfloat16((v1 - mean) * rs * w[lane + 64] + b[lane + 64]);
}

// ---------------- in-proj MFMA GEMM: xz = xn(rev for z=1) @ in_w -> xpre|zb (bf16) ----
__global__ __launch_bounds__(256) void mgemm_in_k(
    const __hip_bfloat16* __restrict__ A,
    const __hip_bfloat16* __restrict__ Wt, size_t wStr,
    __hip_bfloat16* __restrict__ O0, __hip_bfloat16* __restrict__ O1) {
    __shared__ __align__(16) __hip_bfloat16 As[64][40];
    __shared__ __align__(16) __hip_bfloat16 Bs[64][40];
    int z = blockIdx.z;
    Wt += (size_t)z * wStr;
    O0 += (size_t)z * CHW;
    O1 += (size_t)z * CHW;
    int m0 = blockIdx.x * 64, n0 = blockIdx.y * 64;
    int tid = threadIdx.x;
    int lane = tid & 63, w = tid >> 6;
    int wm = w >> 1, wn = w & 1;
    int lr = lane & 15, lh = lane >> 4;
    int rowL = tid >> 2, cc = tid & 3;
    floatx4 acc[2][2] = {};
    for (int k0 = 0; k0 < DM; k0 += 32) {
        int am = m0 + rowL;
        if (z) am = FLIP(am);
        *(float4*)&As[rowL][cc * 8] = *(const float4*)&A[(size_t)am * DM + k0 + cc * 8];
        *(float4*)&Bs[rowL][cc * 8] = *(const float4*)&Wt[(size_t)(n0 + rowL) * DM + k0 + cc * 8];
        __syncthreads();
        short8 a0 = *(const short8*)&As[wm * 32 + lr][lh * 8];
        short8 a1 = *(const short8*)&As[wm * 32 + 16 + lr][lh * 8];
        short8 b0 = *(const short8*)&Bs[wn * 32 + lr][lh * 8];
        short8 b1 = *(const short8*)&Bs[wn * 32 + 16 + lr][lh * 8];
        acc[0][0] = __builtin_amdgcn_mfma_f32_16x16x32_bf16(a0, b0, acc[0][0], 0, 0, 0);
        acc[1][0] = __builtin_amdgcn_mfma_f32_16x16x32_bf16(a1, b0, acc[1][0], 0, 0, 0);
        acc[0][1] = __builtin_amdgcn_mfma_f32_16x16x32_bf16(a0, b1, acc[0][1], 0, 0, 0);
        acc[1][1] = __builtin_amdgcn_mfma_f32_16x16x32_bf16(a1, b1, acc[1][1], 0, 0, 0);
        __syncthreads();
    }
#pragma unroll
    for (int mf = 0; mf < 2; mf++)
#pragma unroll
        for (int nf = 0; nf < 2; nf++)
#pragma unroll
            for (int r = 0; r < 4; r++) {
                int row = m0 + wm * 32 + mf * 16 + lh * 4 + r;
                int col = n0 + wn * 32 + nf * 16 + lr;
                __hip_bfloat16 v = __float2bfloat16(acc[mf][nf][r]);
                if (col < DI) O0[(size_t)row * DI + col] = v;
                else O1[(size_t)row * DI + col - DI] = v;
            }
}

// ---------------- out-proj MFMA GEMM: ytmp[z] = y[z] @ out_w[z] + bias[z] (f32) ------
__global__ __launch_bounds__(256) void mgemm_out_k(
    const __hip_bfloat16* __restrict__ A,
    const __hip_bfloat16* __restrict__ Wt, size_t wStr,
    const float* __restrict__ bias,
    float* __restrict__ O) {
    __shared__ __align__(16) __hip_bfloat16 As[64][40];
    __shared__ __align__(16) __hip_bfloat16 Bs[64][40];
    int z = blockIdx.z;
    A += (size_t)z * CHW;
    Wt += (size_t)z * wStr;
    bias += z * DM;
    O += (size_t)z * PT * DM;
    int m0 = blockIdx.x * 64, n0 = blockIdx.y * 64;
    int tid = threadIdx.x;
    int lane = tid & 63, w = tid >> 6;
    int wm = w >> 1, wn = w & 1;
    int lr = lane & 15, lh = lane >> 4;
    int rowL = tid >> 2, cc = tid & 3;
    floatx4 acc[2][2] = {};
    for (int k0 = 0; k0 < DI; k0 += 32) {
        *(float4*)&As[rowL][cc * 8] = *(const float4*)&A[(size_t)(m0 + rowL) * DI + k0 + cc * 8];
        *(float4*)&Bs[rowL][cc * 8] = *(const float4*)&Wt[(size_t)(n0 + rowL) * DI + k0 + cc * 8];
        __syncthreads();
        short8 a0 = *(const short8*)&As[wm * 32 + lr][lh * 8];
        short8 a1 = *(const short8*)&As[wm * 32 + 16 + lr][lh * 8];
        short8 b0 = *(const short8*)&Bs[wn * 32 + lr][lh * 8];
        short8 b1 = *(const short8*)&Bs[wn * 32 + 16 + lr][lh * 8];
        acc[0][0] = __builtin_amdgcn_mfma_f32_16x16x32_bf16(a0, b0, acc[0][0], 0, 0, 0);
        acc[1][0] = __builtin_amdgcn_mfma_f32_16x16x32_bf16(a1, b0, acc[1][0], 0, 0, 0);
        acc[0][1] = __builtin_amdgcn_mfma_f32_16x16x32_bf16(a0, b1, acc[0][1], 0, 0, 0);
        acc[1][1] = __builtin_amdgcn_mfma_f32_16x16x32_bf16(a1, b1, acc[1][1], 0, 0, 0);
        __syncthreads();
    }
#pragma unroll
    for (int mf = 0; mf < 2; mf++)
#pragma unroll
        for (int nf = 0; nf < 2; nf++)
#pragma unroll
            for (int r = 0; r < 4; r++) {
                int row = m0 + wm * 32 + mf * 16 + lh * 4 + r;
                int col = n0 + wn * 32 + nf * 16 + lr;
                O[(size_t)row * DM + col] = acc[mf][nf][r] + bias[col];
            }
}

// ---------------- xp GEMM with fused conv+silu A-load (bf16 xpre in) ----------------
__global__ __launch_bounds__(256) void xpgemm_k(
    const __hip_bfloat16* __restrict__ xpre,
    const __hip_bfloat16* __restrict__ Wt, size_t wStr,
    const float* __restrict__ cw, const float* __restrict__ cb,
    float* __restrict__ xdbl, __hip_bfloat16* __restrict__ xsil) {
    __shared__ __align__(16) __hip_bfloat16 As[64][40];
    __shared__ __align__(16) __hip_bfloat16 Bs[64][40];
    int z = blockIdx.z;
    const __hip_bfloat16* xp = xpre + (size_t)z * CHW;
    const __hip_bfloat16* wt = Wt + (size_t)z * wStr;
    const float* cwz = cw + z * DI * DC;
    const float* cbz = cb + z * DI;
    float* xd = xdbl + (size_t)z * PT * 40;
    __hip_bfloat16* xsz = xsil + (size_t)z * CHW;
    int m0 = blockIdx.x * 64;
    int tid = threadIdx.x;
    int lane = tid & 63, w = tid >> 6;
    int wm = w >> 1, wn = w & 1;
    int lr = lane & 15, lh = lane >> 4;
    int rowL = tid >> 2, cc = tid & 3;
    int m = m0 + rowL;
    int tloc = m & (NT - 1);
    floatx4 acc[2][2] = {};
    for (int k0 = 0; k0 < DI; k0 += 32) {
        int d0 = k0 + cc * 8;
        float a8[8];
#pragma unroll
        for (int jj = 0; jj < 8; jj++) a8[jj] = cbz[d0 + jj];
#pragma unroll
        for (int j = 0; j < DC; j++) {
            if (tloc - 3 + j >= 0) {
                const __hip_bfloat16* src = &xp[(size_t)(m - 3 + j) * DI + d0];
#pragma unroll
                for (int jj = 0; jj < 8; jj++)
                    a8[jj] += __bfloat162float(src[jj]) * cwz[(d0 + jj) * DC + j];
            }
        }
        __align__(16) __hip_bfloat16 h8[8];
#pragma unroll
        for (int jj = 0; jj < 8; jj++) {
            float v = a8[jj];
            v = v / (1.f + __expf(-v));
            h8[jj] = __float2bfloat16(v);
        }
        *(float4*)&As[rowL][cc * 8] = *(const float4*)h8;
        *(float4*)&xsz[(size_t)m * DI + d0] = *(const float4*)h8;
        float4 bv = {0.f, 0.f, 0.f, 0.f};
        if (rowL < 40) bv = *(const float4*)&wt[(size_t)rowL * DI + k0 + cc * 8];
        *(float4*)&Bs[rowL][cc * 8] = bv;
        __syncthreads();
        short8 a0 = *(const short8*)&As[wm * 32 + lr][lh * 8];
        short8 a1 = *(const short8*)&As[wm * 32 + 16 + lr][lh * 8];
        short8 b0 = *(const short8*)&Bs[wn * 32 + lr][lh * 8];
        short8 b1 = *(const short8*)&Bs[wn * 32 + 16 + lr][lh * 8];
        acc[0][0] = __builtin_amdgcn_mfma_f32_16x16x32_bf16(a0, b0, acc[0][0], 0, 0, 0);
        acc[1][0] = __builtin_amdgcn_mfma_f32_16x16x32_bf16(a1, b0, acc[1][0], 0, 0, 0);
        acc[0][1] = __builtin_amdgcn_mfma_f32_16x16x32_bf16(a0, b1, acc[0][1], 0, 0, 0);
        acc[1][1] = __builtin_amdgcn_mfma_f32_16x16x32_bf16(a1, b1, acc[1][1], 0, 0, 0);
        __syncthreads();
    }
#pragma unroll
    for (int mf = 0; mf < 2; mf++)
#pragma unroll
        for (int nf = 0; nf < 2; nf++)
#pragma unroll
            for (int r = 0; r < 4; r++) {
                int row = m0 + wm * 32 + mf * 16 + lh * 4 + r;
                int col = wn * 32 + nf * 16 + lr;
                if (col < 40) xd[(size_t)row * 40 + col] = acc[mf][nf][r];
            }
}

// ---------------- dt: delta = softplus(dt @ dt_w + dt_b) -> bf16 ----------------
__global__ void dt_k(const float* __restrict__ xdbl, const float* __restrict__ dt_w,
                     const float* __restrict__ dt_b, __hip_bfloat16* __restrict__ deltab) {
    int g = blockIdx.x * 256 + threadIdx.x;   // 2*PT*DI
    int d = g & 255;
    int row = g >> 8;
    int r = row >> 13;
    const float* xr = xdbl + (size_t)row * 40;
    float acc = dt_b[r * DI + d];
#pragma unroll
    for (int j = 0; j < DR; j++)
        acc += xr[j] * dt_w[(r * DR + j) * DI + d];
    float sp = fmaxf(acc, 0.f) + log1pf(__expf(-fabsf(acc)));
    deltab[g] = __float2bfloat16(sp);
}

// ---------------- scan pass 1: 4 lanes/channel, 4 states/lane ----------------
// g: sg=g&3, chan=(g>>2)&4095 (d=chan&255,b=(chan>>8)&7,r=chan>>11), c=g>>14
__global__ __launch_bounds__(256) void scan1_k(
    const __hip_bfloat16* __restrict__ deltab, const __hip_bfloat16* __restrict__ xsil,
    const float* __restrict__ xdbl, const float* __restrict__ A_log,
    float* __restrict__ smryA, float* __restrict__ smryH) {
    int g = blockIdx.x * 256 + threadIdx.x;   // 4*NCH*NCHUNK = 524288
    int sg = g & 3;
    int chan = (g >> 2) & (NCH - 1);
    int c = g >> 14;
    int d = chan & 255, b = (chan >> 8) & 7, r = chan >> 11;
    size_t cbase = (size_t)(r * 8 + b) * (NT * DI) + d;
    const __hip_bfloat16* del = deltab + cbase;
    const __hip_bfloat16* xr = xsil + cbase;
    const float* xd = xdbl + (size_t)(r * PT + b * NT) * 40;
    float Av[4], hs[4] = {0.f, 0.f, 0.f, 0.f}, ap[4] = {1.f, 1.f, 1.f, 1.f};
#pragma unroll
    for (int i = 0; i < 4; i++)
        Av[i] = -__expf(A_log[(r * DI + d) * DS + sg * 4 + i]);
    int t0 = c * CL;
    for (int t = t0; t < t0 + CL; t++) {
        float dl = __bfloat162float(del[t * DI]);
        float xv = __bfloat162float(xr[t * DI]);
        float u = dl * xv;
        float Bv[4];
        *(float4*)Bv = *(const float4*)(xd + t * 40 + DR + sg * 4);
#pragma unroll
        for (int i = 0; i < 4; i++) {
            float dA = __expf(dl * Av[i]);
            ap[i] *= dA;
            hs[i] = dA * hs[i] + u * Bv[i];
        }
    }
    size_t so = ((size_t)c * NCH + chan) * 16 + sg * 4;
    *(float4*)(smryA + so) = *(const float4*)ap;
    *(float4*)(smryH + so) = *(const float4*)hs;
}

// ---------------- scan pass 2: fold + local scan + gated y (bf16) ----------------
__global__ __launch_bounds__(256) void scan2_k(
    const __hip_bfloat16* __restrict__ deltab, const __hip_bfloat16* __restrict__ xsil,
    const __hip_bfloat16* __restrict__ zb, const float* __restrict__ xdbl,
    const float* __restrict__ A_log, const float* __restrict__ Dp,
    const float* __restrict__ smryA, const float* __restrict__ smryH,
    __hip_bfloat16* __restrict__ y) {
    int g = blockIdx.x * 256 + threadIdx.x;   // 524288
    int sg = g & 3;
    int chan = (g >> 2) & (NCH - 1);
    int c = g >> 14;
    int d = chan & 255, b = (chan >> 8) & 7, r = chan >> 11;
    size_t cbase = (size_t)(r * 8 + b) * (NT * DI) + d;
    const __hip_bfloat16* del = deltab + cbase;
    const __hip_bfloat16* xr = xsil + cbase;
    const __hip_bfloat16* zr = zb + cbase;
    const float* xd = xdbl + (size_t)(r * PT + b * NT) * 40;
    __hip_bfloat16* yr = y + cbase;
    float Av[4], hs[4] = {0.f, 0.f, 0.f, 0.f};
#pragma unroll
    for (int i = 0; i < 4; i++)
        Av[i] = -__expf(A_log[(r * DI + d) * DS + sg * 4 + i]);
    for (int j = 0; j < c; j++) {
        size_t so = ((size_t)j * NCH + chan) * 16 + sg * 4;
        float aj[4], hj[4];
        *(float4*)aj = *(const float4*)(smryA + so);
        *(float4*)hj = *(const float4*)(smryH + so);
#pragma unroll
        for (int i = 0; i < 4; i++) hs[i] = aj[i] * hs[i] + hj[i];
    }
    float Dv = Dp[r * DI + d];
    int t0 = c * CL;
    for (int t = t0; t < t0 + CL; t++) {
        float dl = __bfloat162float(del[t * DI]);
        float xv = __bfloat162float(xr[t * DI]);
        float u = dl * xv;
        float Bv[4], Cv[4];
        *(float4*)Bv = *(const float4*)(xd + t * 40 + DR + sg * 4);
        *(float4*)Cv = *(const float4*)(xd + t * 40 + DR + DS + sg * 4);
        float py = 0.f;
#pragma unroll
        for (int i = 0; i < 4; i++) {
            float dA = __expf(dl * Av[i]);
            hs[i] = dA * hs[i] + u * Bv[i];
            py += hs[i] * Cv[i];
        }
        py += __shfl_xor(py, 1);
        py += __shfl_xor(py, 2);
        if (sg == 0) {
            float zv = __bfloat162float(zr[t * DI]);
            float sig = 1.f / (1.f + __expf(-zv));
            yr[t * DI] = __float2bfloat16((py + Dv * xv) * (zv * sig));
        }
    }
}

// ---------------- partial pool: sum (h + y0 + flip(y1)) over 64-t chunks ----------------
__global__ void pooladd_k(const float* __restrict__ h, const float* __restrict__ ytmp,
                          float* __restrict__ partial) {
    int b = blockIdx.x, tc = blockIdx.y, m = threadIdx.x;  // 8 x 16, 128 thr
    float acc = 0.f;
    for (int i = 0; i < 64; i++) {
        int row = b * NT + tc * 64 + i;
        acc += h[(size_t)row * DM + m] + ytmp[(size_t)row * DM + m]
             + ytmp[(size_t)PT * DM + (size_t)FLIP(row) * DM + m];
    }
    partial[(b * 16 + tc) * DM + m] = acc;
}

// ---------------- classifier ----------------
__global__ __launch_bounds__(128) void cls_k(
    const float* __restrict__ partial, const float* __restrict__ lw,
    const float* __restrict__ lb, const float* __restrict__ W1,
    const float* __restrict__ b1, const float* __restrict__ W2,
    const float* __restrict__ b2, float* __restrict__ out) {
    __shared__ float red[128], pbuf[128], qbuf[64];
    int b = blockIdx.x, i = threadIdx.x;
    float v = 0.f;
    for (int tc = 0; tc < 16; tc++) v += partial[(b * 16 + tc) * DM + i];
    v *= (1.f / NT);
    red[i] = v;
    __syncthreads();
    for (int o = 64; o > 0; o >>= 1) { if (i < o) red[i] += red[i + o]; __syncthreads(); }
    float mean = red[0] * (1.f / 128.f);
    __syncthreads();
    red[i] = (v - mean) * (v - mean);
    __syncthreads();
    for (int o = 64; o > 0; o >>= 1) { if (i < o) red[i] += red[i + o]; __syncthreads(); }
    float var = red[0] * (1.f / 128.f);
    float p = (v - mean) * rsqrtf(var + 1e-5f) * lw[i] + lb[i];
    pbuf[i] = p;
    __syncthreads();
    if (i < 64) {
        float acc = b1[i];
        for (int k = 0; k < 128; k++) acc += pbuf[k] * W1[k * 64 + i];
        float x = acc;
        float tt = tanhf(0.7978845608028654f * (x + 0.044715f * x * x * x));
        qbuf[i] = 0.5f * x * (1.f + tt);
    }
    __syncthreads();
    if (i == 0) {
        float acc = b2[0];
        for (int k = 0; k < 64; k++) acc += qbuf[k] * W2[k];
        out[b] = acc;
    }
}

extern "C" void kernel_launch(void* const* d_in, const int* in_sizes, int n_in,
                              void* d_out, int out_size, void* d_ws, size_t ws_size,
                              hipStream_t stream) {
    const float* eeg    = (const float*)d_in[0];
    const float* Win    = (const float*)d_in[1];
    const float* b_in   = (const float*)d_in[2];
    const float* ln_w   = (const float*)d_in[3];
    const float* ln_b   = (const float*)d_in[4];
    const float* in_w   = (const float*)d_in[5];
    const float* conv_w = (const float*)d_in[6];
    const float* conv_b = (const float*)d_in[7];
    const float* xp_w   = (const float*)d_in[8];
    const float* dt_w   = (const float*)d_in[9];
    const float* dt_b   = (const float*)d_in[10];
    const float* A_log  = (const float*)d_in[11];
    const float* Dp     = (const float*)d_in[12];
    const float* out_w  = (const float*)d_in[13];
    const float* out_b  = (const float*)d_in[14];
    const float* clw    = (const float*)d_in[15];
    const float* clb    = (const float*)d_in[16];
    const float* W1     = (const float*)d_in[17];
    const float* b1     = (const float*)d_in[18];
    const float* W2     = (const float*)d_in[19];
    const float* b2     = (const float*)d_in[20];
    float* out = (float*)d_out;

    float* ws = (float*)d_ws;
    float* h      = ws;                          // 1,048,576 f32
    float* xdbl   = h + PT * DM;                 // 655,360 f32
    float* smryA  = xdbl + 2 * PT * 40;          // 2,097,152 f32 (ytmp overlays)
    float* smryH  = smryA + NCHUNK * NCH * 16;   // 2,097,152 f32
    float* partial = smryH + NCHUNK * NCH * 16;  // 16,384 f32
    float* ytmp   = smryA;                       // [2][PT][DM] = 2,097,152 f32
    __hip_bfloat16* xnb    = (__hip_bfloat16*)(partial + 16384);  // 1,048,576
    __hip_bfloat16* xpreb  = xnb + PT * DM;                       // 4,194,304
    __hip_bfloat16* zbb    = xpreb + 2 * CHW;                     // 4,194,304
    __hip_bfloat16* xsilb  = zbb + 2 * CHW;                       // 4,194,304
    __hip_bfloat16* deltab = xsilb + 2 * CHW;                     // 4,194,304
    __hip_bfloat16* yb     = deltab + 2 * CHW;                    // 4,194,304
    __hip_bfloat16* wT     = yb + 2 * CHW;                        // 868,352
    __hip_bfloat16* wTin   = wT;
    __hip_bfloat16* wTxp   = wT + 524288;
    __hip_bfloat16* wTout  = wT + 606208;

    wprep_k<<<3392, 256, 0, stream>>>(in_w, xp_w, out_w, wT);
    embed_k<<<PT * DM / 256, 256, 0, stream>>>(eeg, Win, b_in, h);

    for (int l = 0; l < NL; l++) {
        lnadd_k<<<PT / 4, 256, 0, stream>>>(h, ytmp, ln_w + l * DM, ln_b + l * DM, xnb, l > 0);
        mgemm_in_k<<<dim3(PT / 64, 8, 2), 256, 0, stream>>>(
            xnb, wTin + (size_t)l * 2 * 65536, 65536, xpreb, zbb);
        xpgemm_k<<<dim3(PT / 64, 1, 2), 256, 0, stream>>>(
            xpreb, wTxp + (size_t)l * 2 * 10240, 10240,
            conv_w + (size_t)l * 2 * DI * DC, conv_b + (size_t)l * 2 * DI,
            xdbl, xsilb);
        dt_k<<<2 * CHW / 256, 256, 0, stream>>>(
            xdbl, dt_w + (size_t)l * 2 * DR * DI, dt_b + (size_t)l * 2 * DI, deltab);
        scan1_k<<<4 * NCHUNK * NCH / 256, 256, 0, stream>>>(
            deltab, xsilb, xdbl, A_log + (size_t)l * 2 * DI * DS, smryA, smryH);
        scan2_k<<<4 * NCHUNK * NCH / 256, 256, 0, stream>>>(
            deltab, xsilb, zbb, xdbl, A_log + (size_t)l * 2 * DI * DS,
            Dp + (size_t)l * 2 * DI, smryA, smryH, yb);
        mgemm_out_k<<<dim3(PT / 64, 2, 2), 256, 0, stream>>>(
            yb, wTout + (size_t)l * 2 * 32768, 32768,
            out_b + (size_t)l * 2 * DM, ytmp);
    }

    pooladd_k<<<dim3(NB, 16), DM, 0, stream>>>(h, ytmp, partial);
    cls_k<<<NB, DM, 0, stream>>>(partial, clw, clb, W1, b1, W2, b2, out);
}

// Round 6
// 463.232 us; speedup vs baseline: 3.7364x; 1.1021x over previous
//
#include <hip/hip_runtime.h>
#include <hip/hip_bf16.h>

#define NB 8
#define NC 16
#define NT 1024
#define DM 128
#define DI 256
#define DS 16
#define DR 8
#define DC 4
#define NL 4
#define NCHUNK 32
#define CL (NT / NCHUNK)      // 32
#define NCH 4096              // 2*8*256 channels (r,b,d)
#define PT (NB * NT)          // 8192
#define CHW (PT * DI)         // 2,097,152

typedef __attribute__((ext_vector_type(8))) short short8;
typedef __attribute__((ext_vector_type(4))) float floatx4;

#define FLIP(m) (((m) & ~(NT - 1)) | ((NT - 1) - ((m) & (NT - 1))))

// ---------------- weight prep: convert + transpose to bf16 [N][K] ----------------
__global__ void wprep_k(const float* __restrict__ in_w, const float* __restrict__ xp_w,
                        const float* __restrict__ out_w, __hip_bfloat16* __restrict__ wT) {
    int i = blockIdx.x * 256 + threadIdx.x;
    if (i < 524288) {
        int g = i >> 16, rem = i & 65535, n = rem >> 7, k = rem & 127;
        wT[i] = __float2bfloat16(in_w[(size_t)g * 65536 + k * 512 + n]);
        return;
    }
    i -= 524288;
    if (i < 81920) {
        int g = i / 10240, rem = i % 10240, n = rem >> 8, k = rem & 255;
        wT[524288 + g * 10240 + n * 256 + k] = __float2bfloat16(xp_w[(size_t)g * 10240 + k * 40 + n]);
        return;
    }
    i -= 81920;
    if (i < 262144) {
        int g = i >> 15, rem = i & 32767, n = rem >> 8, k = rem & 255;
        wT[606208 + g * 32768 + n * 256 + k] = __float2bfloat16(out_w[(size_t)g * 32768 + k * 128 + n]);
    }
}

// ---------------- embed ----------------
__global__ void embed_k(const float* __restrict__ eeg, const float* __restrict__ Win,
                        const float* __restrict__ b_in, float* __restrict__ h) {
    int g = blockIdx.x * 256 + threadIdx.x;
    int m = g & 127;
    int t = (g >> 7) & 1023;
    int b = g >> 17;
    float acc = b_in[m];
#pragma unroll
    for (int c = 0; c < NC; c++)
        acc += eeg[(b * NC + c) * NT + t] * Win[c * DM + m];
    h[g] = acc;
}

// ---------------- residual add (fwd + flipped bwd) + layernorm -> bf16 ----------------
__global__ void lnadd_k(float* __restrict__ hbuf, const float* __restrict__ ytmp,
                        const float* __restrict__ w, const float* __restrict__ b,
                        __hip_bfloat16* __restrict__ xn, int doAdd) {
    int lane = threadIdx.x & 63;
    int row = (blockIdx.x * 256 + threadIdx.x) >> 6;
    float* hr = hbuf + (size_t)row * DM;
    float v0 = hr[lane], v1 = hr[lane + 64];
    if (doAdd) {
        const float* y0 = ytmp + (size_t)row * DM;
        const float* y1 = ytmp + (size_t)PT * DM + (size_t)FLIP(row) * DM;
        v0 += y0[lane] + y1[lane];
        v1 += y0[lane + 64] + y1[lane + 64];
        hr[lane] = v0;
        hr[lane + 64] = v1;
    }
    float s = v0 + v1, s2 = v0 * v0 + v1 * v1;
#pragma unroll
    for (int o = 1; o < 64; o <<= 1) {
        s += __shfl_xor(s, o);
        s2 += __shfl_xor(s2, o);
    }
    float mean = s * (1.f / 128.f);
    float var = s2 * (1.f / 128.f) - mean * mean;
    float rs = rsqrtf(var + 1e-5f);
    xn[(size_t)row * DM + lane]      = __float2bfloat16((v0 - mean) * rs * w[lane] + b[lane]);
    xn[(size_t)row * DM + lane + 64] = __float2bfloat16((v1 - mean) * rs * w[lane + 64] + b[lane + 64]);
}

// ---------------- in-proj MFMA GEMM: xz = xn(rev for z=1) @ in_w -> xpre|zb (bf16) ----
__global__ __launch_bounds__(256) void mgemm_in_k(
    const __hip_bfloat16* __restrict__ A,
    const __hip_bfloat16* __restrict__ Wt, size_t wStr,
    __hip_bfloat16* __restrict__ O0, __hip_bfloat16* __restrict__ O1) {
    __shared__ __align__(16) __hip_bfloat16 As[64][40];
    __shared__ __align__(16) __hip_bfloat16 Bs[64][40];
    int z = blockIdx.z;
    Wt += (size_t)z * wStr;
    O0 += (size_t)z * CHW;
    O1 += (size_t)z * CHW;
    int m0 = blockIdx.x * 64, n0 = blockIdx.y * 64;
    int tid = threadIdx.x;
    int lane = tid & 63, w = tid >> 6;
    int wm = w >> 1, wn = w & 1;
    int lr = lane & 15, lh = lane >> 4;
    int rowL = tid >> 2, cc = tid & 3;
    floatx4 acc[2][2] = {};
    for (int k0 = 0; k0 < DM; k0 += 32) {
        int am = m0 + rowL;
        if (z) am = FLIP(am);
        *(float4*)&As[rowL][cc * 8] = *(const float4*)&A[(size_t)am * DM + k0 + cc * 8];
        *(float4*)&Bs[rowL][cc * 8] = *(const float4*)&Wt[(size_t)(n0 + rowL) * DM + k0 + cc * 8];
        __syncthreads();
        short8 a0 = *(const short8*)&As[wm * 32 + lr][lh * 8];
        short8 a1 = *(const short8*)&As[wm * 32 + 16 + lr][lh * 8];
        short8 b0 = *(const short8*)&Bs[wn * 32 + lr][lh * 8];
        short8 b1 = *(const short8*)&Bs[wn * 32 + 16 + lr][lh * 8];
        acc[0][0] = __builtin_amdgcn_mfma_f32_16x16x32_bf16(a0, b0, acc[0][0], 0, 0, 0);
        acc[1][0] = __builtin_amdgcn_mfma_f32_16x16x32_bf16(a1, b0, acc[1][0], 0, 0, 0);
        acc[0][1] = __builtin_amdgcn_mfma_f32_16x16x32_bf16(a0, b1, acc[0][1], 0, 0, 0);
        acc[1][1] = __builtin_amdgcn_mfma_f32_16x16x32_bf16(a1, b1, acc[1][1], 0, 0, 0);
        __syncthreads();
    }
#pragma unroll
    for (int mf = 0; mf < 2; mf++)
#pragma unroll
        for (int nf = 0; nf < 2; nf++)
#pragma unroll
            for (int r = 0; r < 4; r++) {
                int row = m0 + wm * 32 + mf * 16 + lh * 4 + r;
                int col = n0 + wn * 32 + nf * 16 + lr;
                __hip_bfloat16 v = __float2bfloat16(acc[mf][nf][r]);
                if (col < DI) O0[(size_t)row * DI + col] = v;
                else O1[(size_t)row * DI + col - DI] = v;
            }
}

// ---------------- out-proj MFMA GEMM: ytmp[z] = y[z] @ out_w[z] + bias[z] (f32) ------
__global__ __launch_bounds__(256) void mgemm_out_k(
    const __hip_bfloat16* __restrict__ A,
    const __hip_bfloat16* __restrict__ Wt, size_t wStr,
    const float* __restrict__ bias,
    float* __restrict__ O) {
    __shared__ __align__(16) __hip_bfloat16 As[64][40];
    __shared__ __align__(16) __hip_bfloat16 Bs[64][40];
    int z = blockIdx.z;
    A += (size_t)z * CHW;
    Wt += (size_t)z * wStr;
    bias += z * DM;
    O += (size_t)z * PT * DM;
    int m0 = blockIdx.x * 64, n0 = blockIdx.y * 64;
    int tid = threadIdx.x;
    int lane = tid & 63, w = tid >> 6;
    int wm = w >> 1, wn = w & 1;
    int lr = lane & 15, lh = lane >> 4;
    int rowL = tid >> 2, cc = tid & 3;
    floatx4 acc[2][2] = {};
    for (int k0 = 0; k0 < DI; k0 += 32) {
        *(float4*)&As[rowL][cc * 8] = *(const float4*)&A[(size_t)(m0 + rowL) * DI + k0 + cc * 8];
        *(float4*)&Bs[rowL][cc * 8] = *(const float4*)&Wt[(size_t)(n0 + rowL) * DI + k0 + cc * 8];
        __syncthreads();
        short8 a0 = *(const short8*)&As[wm * 32 + lr][lh * 8];
        short8 a1 = *(const short8*)&As[wm * 32 + 16 + lr][lh * 8];
        short8 b0 = *(const short8*)&Bs[wn * 32 + lr][lh * 8];
        short8 b1 = *(const short8*)&Bs[wn * 32 + 16 + lr][lh * 8];
        acc[0][0] = __builtin_amdgcn_mfma_f32_16x16x32_bf16(a0, b0, acc[0][0], 0, 0, 0);
        acc[1][0] = __builtin_amdgcn_mfma_f32_16x16x32_bf16(a1, b0, acc[1][0], 0, 0, 0);
        acc[0][1] = __builtin_amdgcn_mfma_f32_16x16x32_bf16(a0, b1, acc[0][1], 0, 0, 0);
        acc[1][1] = __builtin_amdgcn_mfma_f32_16x16x32_bf16(a1, b1, acc[1][1], 0, 0, 0);
        __syncthreads();
    }
#pragma unroll
    for (int mf = 0; mf < 2; mf++)
#pragma unroll
        for (int nf = 0; nf < 2; nf++)
#pragma unroll
            for (int r = 0; r < 4; r++) {
                int row = m0 + wm * 32 + mf * 16 + lh * 4 + r;
                int col = n0 + wn * 32 + nf * 16 + lr;
                O[(size_t)row * DM + col] = acc[mf][nf][r] + bias[col];
            }
}

// ---------------- xp GEMM with fused conv+silu A-load (bf16 xpre in) ----------------
__global__ __launch_bounds__(256) void xpgemm_k(
    const __hip_bfloat16* __restrict__ xpre,
    const __hip_bfloat16* __restrict__ Wt, size_t wStr,
    const float* __restrict__ cw, const float* __restrict__ cb,
    float* __restrict__ xdbl, __hip_bfloat16* __restrict__ xsil) {
    __shared__ __align__(16) __hip_bfloat16 As[64][40];
    __shared__ __align__(16) __hip_bfloat16 Bs[64][40];
    int z = blockIdx.z;
    const __hip_bfloat16* xp = xpre + (size_t)z * CHW;
    const __hip_bfloat16* wt = Wt + (size_t)z * wStr;
    const float* cwz = cw + z * DI * DC;
    const float* cbz = cb + z * DI;
    float* xd = xdbl + (size_t)z * PT * 40;
    __hip_bfloat16* xsz = xsil + (size_t)z * CHW;
    int m0 = blockIdx.x * 64;
    int tid = threadIdx.x;
    int lane = tid & 63, w = tid >> 6;
    int wm = w >> 1, wn = w & 1;
    int lr = lane & 15, lh = lane >> 4;
    int rowL = tid >> 2, cc = tid & 3;
    int m = m0 + rowL;
    int tloc = m & (NT - 1);
    floatx4 acc[2][2] = {};
    for (int k0 = 0; k0 < DI; k0 += 32) {
        int d0 = k0 + cc * 8;
        float a8[8];
#pragma unroll
        for (int jj = 0; jj < 8; jj++) a8[jj] = cbz[d0 + jj];
#pragma unroll
        for (int j = 0; j < DC; j++) {
            if (tloc - 3 + j >= 0) {
                const __hip_bfloat16* src = &xp[(size_t)(m - 3 + j) * DI + d0];
#pragma unroll
                for (int jj = 0; jj < 8; jj++)
                    a8[jj] += __bfloat162float(src[jj]) * cwz[(d0 + jj) * DC + j];
            }
        }
        __align__(16) __hip_bfloat16 h8[8];
#pragma unroll
        for (int jj = 0; jj < 8; jj++) {
            float v = a8[jj];
            v = v / (1.f + __expf(-v));
            h8[jj] = __float2bfloat16(v);
        }
        *(float4*)&As[rowL][cc * 8] = *(const float4*)h8;
        *(float4*)&xsz[(size_t)m * DI + d0] = *(const float4*)h8;
        float4 bv = {0.f, 0.f, 0.f, 0.f};
        if (rowL < 40) bv = *(const float4*)&wt[(size_t)rowL * DI + k0 + cc * 8];
        *(float4*)&Bs[rowL][cc * 8] = bv;
        __syncthreads();
        short8 a0 = *(const short8*)&As[wm * 32 + lr][lh * 8];
        short8 a1 = *(const short8*)&As[wm * 32 + 16 + lr][lh * 8];
        short8 b0 = *(const short8*)&Bs[wn * 32 + lr][lh * 8];
        short8 b1 = *(const short8*)&Bs[wn * 32 + 16 + lr][lh * 8];
        acc[0][0] = __builtin_amdgcn_mfma_f32_16x16x32_bf16(a0, b0, acc[0][0], 0, 0, 0);
        acc[1][0] = __builtin_amdgcn_mfma_f32_16x16x32_bf16(a1, b0, acc[1][0], 0, 0, 0);
        acc[0][1] = __builtin_amdgcn_mfma_f32_16x16x32_bf16(a0, b1, acc[0][1], 0, 0, 0);
        acc[1][1] = __builtin_amdgcn_mfma_f32_16x16x32_bf16(a1, b1, acc[1][1], 0, 0, 0);
        __syncthreads();
    }
#pragma unroll
    for (int mf = 0; mf < 2; mf++)
#pragma unroll
        for (int nf = 0; nf < 2; nf++)
#pragma unroll
            for (int r = 0; r < 4; r++) {
                int row = m0 + wm * 32 + mf * 16 + lh * 4 + r;
                int col = wn * 32 + nf * 16 + lr;
                if (col < 40) xd[(size_t)row * 40 + col] = acc[mf][nf][r];
            }
}

// ---------------- scan pass 1: LDS-staged, fused dt, chunk summaries ----------------
// block = (64 channels, 1 chunk). thread: ch = tid>>2, sg = tid&3.
__global__ __launch_bounds__(256) void scan1_k(
    const __hip_bfloat16* __restrict__ xsil, const float* __restrict__ xdbl,
    const float* __restrict__ dt_w, const float* __restrict__ dt_b,
    const float* __restrict__ A_log,
    __hip_bfloat16* __restrict__ deltab,
    float* __restrict__ smryA, float* __restrict__ smryH) {
    int cblk = blockIdx.y;
    int chan0 = blockIdx.x * 64;
    int rb = chan0 >> 8;
    int d0 = chan0 & 255;
    int r = chan0 >> 11;
    int tid = threadIdx.x;
    int ch = tid >> 2, sg = tid & 3;
    int t0 = cblk * CL;
    __shared__ uint x_s[CL * 32];
    __shared__ float bc_s[CL * 40];
    __shared__ __hip_bfloat16 del_s[CL][64];
    // stage x tile (32 t x 64 d bf16, dword loads)
    const uint* gx = (const uint*)(xsil + (size_t)rb * NT * DI + (size_t)t0 * DI + d0);
#pragma unroll
    for (int k = 0; k < 4; k++) {
        int e = tid + k * 256;
        x_s[e] = gx[(e >> 5) * 128 + (e & 31)];
    }
    // stage xdbl rows (40 floats x 32 t, contiguous)
    const float* gxd = xdbl + (size_t)rb * NT * 40 + (size_t)t0 * 40;
#pragma unroll
    for (int k = 0; k < 5; k++) {
        int e = tid + k * 256;
        bc_s[e] = gxd[e];
    }
    __syncthreads();
    // fused dt: delta tile (32 t x 64 d), 8 outputs/thread
    const float* dwr = dt_w + r * DR * DI;
#pragma unroll
    for (int q = 0; q < 8; q++) {
        int idx = tid + q * 256;
        int tt = idx >> 6, dd = idx & 63;
        int d = d0 + dd;
        float acc = dt_b[r * DI + d];
#pragma unroll
        for (int j = 0; j < 8; j++) acc += bc_s[tt * 40 + j] * dwr[j * DI + d];
        float sp = fmaxf(acc, 0.f) + log1pf(__expf(-fabsf(acc)));
        del_s[tt][dd] = __float2bfloat16(sp);
    }
    __syncthreads();
    // local scan
    float Av[4], hs[4] = {0.f, 0.f, 0.f, 0.f}, ap[4] = {1.f, 1.f, 1.f, 1.f};
#pragma unroll
    for (int i = 0; i < 4; i++)
        Av[i] = -__expf(A_log[(r * DI + d0 + ch) * DS + sg * 4 + i]);
    const __hip_bfloat16* xb = (const __hip_bfloat16*)x_s;
    for (int tt = 0; tt < CL; tt++) {
        float dl = __bfloat162float(del_s[tt][ch]);
        float xv = __bfloat162float(xb[tt * 64 + ch]);
        float u = dl * xv;
        float4 Bv = *(const float4*)&bc_s[tt * 40 + DR + sg * 4];
        float bb[4];
        *(float4*)bb = Bv;
#pragma unroll
        for (int i = 0; i < 4; i++) {
            float dA = __expf(dl * Av[i]);
            ap[i] *= dA;
            hs[i] = dA * hs[i] + u * bb[i];
        }
    }
    // write delta tile to global (for scan2)
    uint* gdel = (uint*)(deltab + (size_t)rb * NT * DI + (size_t)t0 * DI + d0);
#pragma unroll
    for (int k = 0; k < 4; k++) {
        int e = tid + k * 256;
        gdel[(e >> 5) * 128 + (e & 31)] = ((const uint*)del_s)[e];
    }
    size_t so = ((size_t)cblk * NCH + chan0 + ch) * 16 + sg * 4;
    *(float4*)(smryA + so) = *(const float4*)ap;
    *(float4*)(smryH + so) = *(const float4*)hs;
}

// ---------------- scanH: prefix-scan summaries -> h0 per chunk ----------------
__global__ void scanH_k(const float* __restrict__ smryA, const float* __restrict__ smryH,
                        float* __restrict__ h0) {
    int g = blockIdx.x * 256 + threadIdx.x;   // NCH*16 = 65536
    float hh = 0.f;
    for (int c = 0; c < NCHUNK; c++) {
        size_t o = (size_t)c * (NCH * 16) + g;
        h0[o] = hh;
        hh = smryA[o] * hh + smryH[o];
    }
}

// ---------------- scan pass 2: LDS-staged local scan + gated y (bf16) ----------------
__global__ __launch_bounds__(256) void scan2_k(
    const __hip_bfloat16* __restrict__ deltab, const __hip_bfloat16* __restrict__ xsil,
    const __hip_bfloat16* __restrict__ zb, const float* __restrict__ xdbl,
    const float* __restrict__ A_log, const float* __restrict__ Dp,
    const float* __restrict__ h0, __hip_bfloat16* __restrict__ y) {
    int cblk = blockIdx.y;
    int chan0 = blockIdx.x * 64;
    int rb = chan0 >> 8;
    int d0 = chan0 & 255;
    int r = chan0 >> 11;
    int tid = threadIdx.x;
    int ch = tid >> 2, sg = tid & 3;
    int t0 = cblk * CL;
    __shared__ uint del_s[CL * 32], x_s[CL * 32], z_s[CL * 32];
    __shared__ float bc_s[CL * 32];
    __shared__ __hip_bfloat16 y_s[CL][64];
    size_t tilebase = (size_t)rb * NT * DI + (size_t)t0 * DI + d0;
    const uint* gd = (const uint*)(deltab + tilebase);
    const uint* gx = (const uint*)(xsil + tilebase);
    const uint* gz = (const uint*)(zb + tilebase);
#pragma unroll
    for (int k = 0; k < 4; k++) {
        int e = tid + k * 256;
        int a = (e >> 5) * 128 + (e & 31);
        del_s[e] = gd[a];
        x_s[e] = gx[a];
        z_s[e] = gz[a];
    }
    const float* gxd = xdbl + (size_t)rb * NT * 40 + (size_t)t0 * 40;
#pragma unroll
    for (int k = 0; k < 4; k++) {
        int e = tid + k * 256;
        bc_s[e] = gxd[(e >> 5) * 40 + DR + (e & 31)];
    }
    float Av[4], hs[4];
#pragma unroll
    for (int i = 0; i < 4; i++)
        Av[i] = -__expf(A_log[(r * DI + d0 + ch) * DS + sg * 4 + i]);
    float4 hv = *(const float4*)(h0 + ((size_t)cblk * NCH + chan0 + ch) * 16 + sg * 4);
    *(float4*)hs = hv;
    float Dv = Dp[r * DI + d0 + ch];
    __syncthreads();
    const __hip_bfloat16* db = (const __hip_bfloat16*)del_s;
    const __hip_bfloat16* xb = (const __hip_bfloat16*)x_s;
    const __hip_bfloat16* zbb2 = (const __hip_bfloat16*)z_s;
    for (int tt = 0; tt < CL; tt++) {
        float dl = __bfloat162float(db[tt * 64 + ch]);
        float xv = __bfloat162float(xb[tt * 64 + ch]);
        float u = dl * xv;
        float bb[4], cv[4];
        *(float4*)bb = *(const float4*)&bc_s[tt * 32 + sg * 4];
        *(float4*)cv = *(const float4*)&bc_s[tt * 32 + 16 + sg * 4];
        float py = 0.f;
#pragma unroll
        for (int i = 0; i < 4; i++) {
            float dA = __expf(dl * Av[i]);
            hs[i] = dA * hs[i] + u * bb[i];
            py += hs[i] * cv[i];
        }
        py += __shfl_xor(py, 1);
        py += __shfl_xor(py, 2);
        if (sg == 0) {
            float zv = __bfloat162float(zbb2[tt * 64 + ch]);
            float sig = 1.f / (1.f + __expf(-zv));
            y_s[tt][ch] = __float2bfloat16((py + Dv * xv) * (zv * sig));
        }
    }
    __syncthreads();
    uint* gy = (uint*)(y + tilebase);
#pragma unroll
    for (int k = 0; k < 4; k++) {
        int e = tid + k * 256;
        gy[(e >> 5) * 128 + (e & 31)] = ((const uint*)y_s)[e];
    }
}

// ---------------- partial pool: sum (h + y0 + flip(y1)) over 64-t chunks ----------------
__global__ void pooladd_k(const float* __restrict__ h, const float* __restrict__ ytmp,
                          float* __restrict__ partial) {
    int b = blockIdx.x, tc = blockIdx.y, m = threadIdx.x;
    float acc = 0.f;
    for (int i = 0; i < 64; i++) {
        int row = b * NT + tc * 64 + i;
        acc += h[(size_t)row * DM + m] + ytmp[(size_t)row * DM + m]
             + ytmp[(size_t)PT * DM + (size_t)FLIP(row) * DM + m];
    }
    partial[(b * 16 + tc) * DM + m] = acc;
}

// ---------------- classifier ----------------
__global__ __launch_bounds__(128) void cls_k(
    const float* __restrict__ partial, const float* __restrict__ lw,
    const float* __restrict__ lb, const float* __restrict__ W1,
    const float* __restrict__ b1, const float* __restrict__ W2,
    const float* __restrict__ b2, float* __restrict__ out) {
    __shared__ float red[128], pbuf[128], qbuf[64];
    int b = blockIdx.x, i = threadIdx.x;
    float v = 0.f;
    for (int tc = 0; tc < 16; tc++) v += partial[(b * 16 + tc) * DM + i];
    v *= (1.f / NT);
    red[i] = v;
    __syncthreads();
    for (int o = 64; o > 0; o >>= 1) { if (i < o) red[i] += red[i + o]; __syncthreads(); }
    float mean = red[0] * (1.f / 128.f);
    __syncthreads();
    red[i] = (v - mean) * (v - mean);
    __syncthreads();
    for (int o = 64; o > 0; o >>= 1) { if (i < o) red[i] += red[i + o]; __syncthreads(); }
    float var = red[0] * (1.f / 128.f);
    float p = (v - mean) * rsqrtf(var + 1e-5f) * lw[i] + lb[i];
    pbuf[i] = p;
    __syncthreads();
    if (i < 64) {
        float acc = b1[i];
        for (int k = 0; k < 128; k++) acc += pbuf[k] * W1[k * 64 + i];
        float x = acc;
        float tt = tanhf(0.7978845608028654f * (x + 0.044715f * x * x * x));
        qbuf[i] = 0.5f * x * (1.f + tt);
    }
    __syncthreads();
    if (i == 0) {
        float acc = b2[0];
        for (int k = 0; k < 64; k++) acc += qbuf[k] * W2[k];
        out[b] = acc;
    }
}

extern "C" void kernel_launch(void* const* d_in, const int* in_sizes, int n_in,
                              void* d_out, int out_size, void* d_ws, size_t ws_size,
                              hipStream_t stream) {
    const float* eeg    = (const float*)d_in[0];
    const float* Win    = (const float*)d_in[1];
    const float* b_in   = (const float*)d_in[2];
    const float* ln_w   = (const float*)d_in[3];
    const float* ln_b   = (const float*)d_in[4];
    const float* in_w   = (const float*)d_in[5];
    const float* conv_w = (const float*)d_in[6];
    const float* conv_b = (const float*)d_in[7];
    const float* xp_w   = (const float*)d_in[8];
    const float* dt_w   = (const float*)d_in[9];
    const float* dt_b   = (const float*)d_in[10];
    const float* A_log  = (const float*)d_in[11];
    const float* Dp     = (const float*)d_in[12];
    const float* out_w  = (const float*)d_in[13];
    const float* out_b  = (const float*)d_in[14];
    const float* clw    = (const float*)d_in[15];
    const float* clb    = (const float*)d_in[16];
    const float* W1     = (const float*)d_in[17];
    const float* b1     = (const float*)d_in[18];
    const float* W2     = (const float*)d_in[19];
    const float* b2     = (const float*)d_in[20];
    float* out = (float*)d_out;

    float* ws = (float*)d_ws;
    float* h      = ws;                          // 1,048,576 f32
    float* xdbl   = h + PT * DM;                 // 655,360 f32
    float* smryA  = xdbl + 2 * PT * 40;          // 2,097,152 f32 (ytmp overlays)
    float* smryH  = smryA + NCHUNK * NCH * 16;   // 2,097,152 f32
    float* h0buf  = smryH + NCHUNK * NCH * 16;   // 2,097,152 f32
    float* partial = h0buf + NCHUNK * NCH * 16;  // 16,384 f32
    float* ytmp   = smryA;                       // [2][PT][DM] overlays smryA
    __hip_bfloat16* xnb    = (__hip_bfloat16*)(partial + 16384);  // 1,048,576
    __hip_bfloat16* xpreb  = xnb + PT * DM;                       // 4,194,304
    __hip_bfloat16* zbb    = xpreb + 2 * CHW;                     // 4,194,304
    __hip_bfloat16* xsilb  = zbb + 2 * CHW;                       // 4,194,304
    __hip_bfloat16* deltab = xsilb + 2 * CHW;                     // 4,194,304
    __hip_bfloat16* yb     = deltab + 2 * CHW;                    // 4,194,304
    __hip_bfloat16* wT     = yb + 2 * CHW;                        // 868,352
    __hip_bfloat16* wTin   = wT;
    __hip_bfloat16* wTxp   = wT + 524288;
    __hip_bfloat16* wTout  = wT + 606208;

    wprep_k<<<3392, 256, 0, stream>>>(in_w, xp_w, out_w, wT);
    embed_k<<<PT * DM / 256, 256, 0, stream>>>(eeg, Win, b_in, h);

    for (int l = 0; l < NL; l++) {
        lnadd_k<<<PT / 4, 256, 0, stream>>>(h, ytmp, ln_w + l * DM, ln_b + l * DM, xnb, l > 0);
        mgemm_in_k<<<dim3(PT / 64, 8, 2), 256, 0, stream>>>(
            xnb, wTin + (size_t)l * 2 * 65536, 65536, xpreb, zbb);
        xpgemm_k<<<dim3(PT / 64, 1, 2), 256, 0, stream>>>(
            xpreb, wTxp + (size_t)l * 2 * 10240, 10240,
            conv_w + (size_t)l * 2 * DI * DC, conv_b + (size_t)l * 2 * DI,
            xdbl, xsilb);
        scan1_k<<<dim3(NCH / 64, NCHUNK), 256, 0, stream>>>(
            xsilb, xdbl, dt_w + (size_t)l * 2 * DR * DI, dt_b + (size_t)l * 2 * DI,
            A_log + (size_t)l * 2 * DI * DS, deltab, smryA, smryH);
        scanH_k<<<NCH * 16 / 256, 256, 0, stream>>>(smryA, smryH, h0buf);
        scan2_k<<<dim3(NCH / 64, NCHUNK), 256, 0, stream>>>(
            deltab, xsilb, zbb, xdbl, A_log + (size_t)l * 2 * DI * DS,
            Dp + (size_t)l * 2 * DI, h0buf, yb);
        mgemm_out_k<<<dim3(PT / 64, 2, 2), 256, 0, stream>>>(
            yb, wTout + (size_t)l * 2 * 32768, 32768,
            out_b + (size_t)l * 2 * DM, ytmp);
    }

    pooladd_k<<<dim3(NB, 16), DM, 0, stream>>>(h, ytmp, partial);
    cls_k<<<NB, DM, 0, stream>>>(partial, clw, clb, W1, b1, W2, b2, out);
}